// Round 1
// baseline (30984.937 us; speedup 1.0000x reference)
//
#include <hip/hip_runtime.h>
#include <hip/hip_bf16.h>
#include <type_traits>

// ---------------------------------------------------------------------------
// Seq2SeqAttention R5: persistent encoder.
//   R4 (29.4 ms) ran 512 serial lstm_mfma launches; weights (21 MB bf16 hi/lo)
//   were re-streamed through L1 every step + per-launch ramp/drain.
//   R5 fuses the encoder into ONE kernel: 256 blocks x 512 thr (1 block/CU
//   guaranteed resident -> deadlock-free grid barrier), Whh/Wih hi+lo staged
//   once into 90 KB LDS (lane-major, conflict-free ds_read_b128), c in a
//   register, sense-reversing grid barrier (agent atomics + threadfence for
//   cross-XCD visibility) between the 512 steps. Math order identical to R4.
//   Decoder / P-GEMM / attention kernels unchanged from R4.
// MFMA 16x16x32 bf16 layouts (m89/m91-verified): A[m=lane&15][k=quad*8+j],
// B[k=quad*8+j][n=lane&15], D col=lane&15 row=quad*4+reg.
// ---------------------------------------------------------------------------

static constexpr int T_ = 512, B_ = 128, I_ = 256, H_ = 1024, O_ = 256;

typedef unsigned short ushort;
typedef __attribute__((ext_vector_type(8))) short bf16x8;
typedef __attribute__((ext_vector_type(4))) float f32x4;
typedef __attribute__((ext_vector_type(8))) unsigned short ushort8_t;
typedef __attribute__((ext_vector_type(8))) _Float16 half8;

__device__ __forceinline__ float bf2f(ushort u) {
    union { unsigned i; float f; } cv; cv.i = ((unsigned)u) << 16; return cv.f;
}
__device__ __forceinline__ ushort f2bf(float f) {   // RNE
    union { float f; unsigned u; } c; c.f = f;
    unsigned r = c.u + 0x7FFFu + ((c.u >> 16) & 1u);
    return (ushort)(r >> 16);
}
__device__ __forceinline__ float fast_sigmoid(float x) { return 1.f / (1.f + __expf(-x)); }
__device__ __forceinline__ float fast_tanh(float x) {
    float ax = fabsf(x);
    float e = __expf(-2.f * ax);
    float t = (1.f - e) / (1.f + e);
    return copysignf(t, x);
}
__device__ __forceinline__ f32x4 mfma16(bf16x8 a, bf16x8 b, f32x4 c) {
    return __builtin_amdgcn_mfma_f32_16x16x32_bf16(a, b, c, 0, 0, 0);
}
__device__ __forceinline__ bf16x8 ld8(const ushort* p) { return *(const bf16x8*)(const void*)p; }

// ---- split 8 fp32 into bf16 hi/lo fragments --------------------------------
__device__ __forceinline__ void split8(const float* p, bf16x8& hi, bf16x8& lo) {
    #pragma unroll
    for (int j = 0; j < 8; j++) {
        const float f = p[j];
        const ushort h = f2bf(f);
        hi[j] = (short)h;
        lo[j] = (short)f2bf(f - bf2f(h));
    }
}

// ---- weight split pre-pass -------------------------------------------------
__global__ __launch_bounds__(256) void split_w(
    const float* __restrict__ src, int srcld, int coloff,
    ushort* __restrict__ hi, ushort* __restrict__ lo, int K)
{
    const int k = blockIdx.x * 256 + threadIdx.x;
    const int r = blockIdx.y;
    const float f = src[(size_t)r * srcld + coloff + k];
    const ushort h = f2bf(f);
    hi[(size_t)r * K + k] = h;
    lo[(size_t)r * K + k] = f2bf(f - bf2f(h));
}

// ---------------------------------------------------------------------------
// Persistent encoder: 256 blocks (1/CU), 512 threads (8 waves). Block owns
// 4 h-values (16 gate-cols) x all 128 batch rows; wave w = row-tile w*16.
// LDS: Whh hi/lo [32 iters][64 lanes][8] + Wih hi/lo [8][64][8] + Gt[16][132].
// Grid barrier between steps; c in register; h hi -> ctx_seq[t], lo ping-pong.
// ---------------------------------------------------------------------------
#define ENC_SMEM_BYTES (32*64*8*2*2 + 8*64*8*2*2 + 16*132*4)   // 90368

__global__ __launch_bounds__(512) void enc_persistent(
    const float* __restrict__ input_seq,
    const ushort* __restrict__ WhhE_h, const ushort* __restrict__ WhhE_l,
    const ushort* __restrict__ WihE_h, const ushort* __restrict__ WihE_l,
    const float* __restrict__ bih, const float* __restrict__ bhh,
    const ushort* __restrict__ hzero,
    ushort* __restrict__ ctx_seq,
    ushort* __restrict__ elo0, ushort* __restrict__ elo1,
    unsigned* __restrict__ bar)           // bar[0]=arrive count, bar[1]=generation
{
    extern __shared__ __align__(16) char smem[];
    ushort* LWh = (ushort*)smem;                 // Whh hi  [32][64][8]
    ushort* LWl = LWh + 32 * 64 * 8;             // Whh lo
    ushort* LIh = LWl + 32 * 64 * 8;             // Wih hi  [8][64][8]
    ushort* LIl = LIh + 8 * 64 * 8;              // Wih lo
    float*  Gt  = (float*)(LIl + 8 * 64 * 8);    // [16 cols][132]

    const int tid  = threadIdx.x;
    const int wave = tid >> 6, lane = tid & 63;
    const int quad = lane >> 4, l15 = lane & 15;
    const int h0   = blockIdx.x << 2;
    const int wr   = ((l15 >> 2) * H_) + h0 + (l15 & 3);   // gate*H + h row of W

    // ---- stage weights into LDS (lane-major fragments; done once) ----
    {
        const size_t woff = (size_t)wr * H_;
        #pragma unroll
        for (int ii = 0; ii < 4; ii++) {
            const int i   = wave + (ii << 3);          // K-iter index 0..31
            const int src = (i << 5) + (quad << 3);
            *(bf16x8*)(LWh + ((i << 6) + lane) * 8) = ld8(WhhE_h + woff + src);
            *(bf16x8*)(LWl + ((i << 6) + lane) * 8) = ld8(WhhE_l + woff + src);
        }
        const size_t ioff = (size_t)wr * I_;
        const int src2 = (wave << 5) + (quad << 3);    // K-iter index = wave (0..7)
        *(bf16x8*)(LIh + ((wave << 6) + lane) * 8) = ld8(WihE_h + ioff + src2);
        *(bf16x8*)(LIl + ((wave << 6) + lane) * 8) = ld8(WihE_l + ioff + src2);
    }

    // per-thread cell-update mapping + persistent state
    const int bl_  = tid >> 2, hl = tid & 3;
    const int hidx = h0 + hl;
    const float bs0 = bih[hidx]           + bhh[hidx];
    const float bs1 = bih[H_ + hidx]      + bhh[H_ + hidx];
    const float bs2 = bih[2 * H_ + hidx]  + bhh[2 * H_ + hidx];
    const float bs3 = bih[3 * H_ + hidx]  + bhh[3 * H_ + hidx];
    float c_reg = 0.f;
    unsigned genv = 0;
    __syncthreads();

    const size_t arow = (size_t)((wave << 4) + l15);   // batch row for MFMA A
    const size_t aoff = arow * H_;
    const size_t xoff = arow * I_;

    for (int t = 0; t < T_; t++) {
        const ushort* hi_in = t ? (ctx_seq + (size_t)(t - 1) * (B_ * H_)) : hzero;
        const ushort* lo_in = (t & 1) ? elo1 : elo0;
        const float*  xs    = input_seq + (size_t)t * (B_ * I_);

        f32x4 acc0 = {0.f, 0.f, 0.f, 0.f}, acc1 = acc0, acc2 = acc0;
        // segment 1: h @ Whh^T (weights from LDS)
        #pragma unroll 4
        for (int kc = 0; kc < H_; kc += 32) {
            const int i = kc >> 5;
            const bf16x8 bh = *(const bf16x8*)(LWh + ((i << 6) + lane) * 8);
            const bf16x8 bl = *(const bf16x8*)(LWl + ((i << 6) + lane) * 8);
            const bf16x8 ah = ld8(hi_in + aoff + kc + (quad << 3));
            const bf16x8 al = ld8(lo_in + aoff + kc + (quad << 3));
            acc0 = mfma16(ah, bh, acc0);
            acc1 = mfma16(ah, bl, acc1);
            acc2 = mfma16(al, bh, acc2);
        }
        // segment 2: x @ Wih^T (x fp32, split on the fly; weights from LDS)
        #pragma unroll
        for (int kc = 0; kc < I_; kc += 32) {
            const int i = kc >> 5;
            const bf16x8 bh = *(const bf16x8*)(LIh + ((i << 6) + lane) * 8);
            const bf16x8 bl = *(const bf16x8*)(LIl + ((i << 6) + lane) * 8);
            bf16x8 ah, al;
            split8(xs + xoff + kc + (quad << 3), ah, al);
            acc0 = mfma16(ah, bh, acc0);
            acc1 = mfma16(ah, bl, acc1);
            acc2 = mfma16(al, bh, acc2);
        }
        // gate exchange: Gt[col][row]; D: row=quad*4+r, col=l15
        #pragma unroll
        for (int r = 0; r < 4; r++)
            Gt[l15 * 132 + (wave << 4) + (quad << 2) + r] = acc0[r] + acc1[r] + acc2[r];
        __syncthreads();

        // cell update (thread -> (batch row bl_, h-local hl)); c in register
        const float gi = Gt[hl * 132 + bl_]        + bs0;
        const float gf = Gt[(4 + hl) * 132 + bl_]  + bs1;
        const float gg = Gt[(8 + hl) * 132 + bl_]  + bs2;
        const float go = Gt[(12 + hl) * 132 + bl_] + bs3;
        const float ig = fast_sigmoid(gi), fg = fast_sigmoid(gf);
        const float gtv = fast_tanh(gg),   og = fast_sigmoid(go);
        c_reg = fg * c_reg + ig * gtv;
        const float hnew = og * fast_tanh(c_reg);
        const size_t oidx = (size_t)bl_ * H_ + hidx;
        const ushort hh = f2bf(hnew);
        ctx_seq[(size_t)t * (B_ * H_) + oidx] = hh;
        ushort* lo_out = ((t + 1) & 1) ? elo1 : elo0;
        lo_out[oidx] = f2bf(hnew - bf2f(hh));

        // grid barrier (skip after last step; kernel end orders vs. stream)
        if (t != T_ - 1) {
            __syncthreads();   // drains vmcnt: all block stores complete before arrive
            if (tid == 0) {
                __threadfence();   // writeback L2 -> LLC (cross-XCD visibility)
                const unsigned arrived =
                    __hip_atomic_fetch_add(&bar[0], 1u, __ATOMIC_RELAXED,
                                           __HIP_MEMORY_SCOPE_AGENT) + 1;
                const unsigned target = ++genv;
                if (arrived == gridDim.x) {
                    __hip_atomic_store(&bar[0], 0u, __ATOMIC_RELAXED,
                                       __HIP_MEMORY_SCOPE_AGENT);
                    __threadfence();   // order reset + acquire others' data
                    __hip_atomic_store(&bar[1], target, __ATOMIC_RELAXED,
                                       __HIP_MEMORY_SCOPE_AGENT);
                } else {
                    while (__hip_atomic_load(&bar[1], __ATOMIC_RELAXED,
                                             __HIP_MEMORY_SCOPE_AGENT) < target)
                        __builtin_amdgcn_s_sleep(2);
                    __threadfence();   // invalidate stale L1/L2 before next-step reads
                }
            }
            __syncthreads();
        }
    }
}

// ---- fused LSTM step (MFMA). Block: 64 batch rows x 16 gate-cols. ----------
// (decoder only now) grid (H/4 = 256 colgroups, 2 row-halves).
template<bool WSPLIT, bool XSPLIT, int KX>
__global__ __launch_bounds__(256) void lstm_mfma(
    const ushort* __restrict__ h_hi, const ushort* __restrict__ h_lo,
    const void* __restrict__ x_p, const ushort* __restrict__ x_lo,
    const void* __restrict__ Whh_a, const void* __restrict__ Whh_b,
    const void* __restrict__ Wih_a, const void* __restrict__ Wih_b,
    const float* __restrict__ bih, const float* __restrict__ bhh,
    const float* __restrict__ c_in, float* __restrict__ c_out,
    ushort* __restrict__ h_out_hi, ushort* __restrict__ h_out_lo)
{
    __shared__ float Gt[16][65];
    const int tid = threadIdx.x;
    const int wave = tid >> 6, lane = tid & 63;
    const int quad = lane >> 4, l15 = lane & 15;
    const int h0 = blockIdx.x << 2;
    const int mbase = (blockIdx.y << 6) + (wave << 4);
    const size_t arow = (size_t)(mbase + l15);
    const int wr = ((l15 >> 2) * H_) + h0 + (l15 & 3);   // gate*H + h index

    f32x4 acc0 = {0.f,0.f,0.f,0.f}, acc1 = acc0, acc2 = acc0;

    // segment 1: h @ Whh^T, K = 1024, A split (hi+lo)
    {
        const size_t aoff = arow * H_;
        const size_t woff = (size_t)wr * H_;
        #pragma unroll 4
        for (int kc = 0; kc < H_; kc += 32) {
            const int ko = kc + quad * 8;
            bf16x8 bh, bl;
            if constexpr (WSPLIT) {
                bh = ld8((const ushort*)Whh_a + woff + ko);
                bl = ld8((const ushort*)Whh_b + woff + ko);
            } else {
                split8((const float*)Whh_a + woff + ko, bh, bl);
            }
            const bf16x8 ah = ld8(h_hi + aoff + ko);
            const bf16x8 al = ld8(h_lo + aoff + ko);
            acc0 = mfma16(ah, bh, acc0);
            acc1 = mfma16(ah, bl, acc1);
            acc2 = mfma16(al, bh, acc2);
        }
    }
    // segment 2: x @ Wih^T, K = KX
    {
        const size_t woff = (size_t)wr * KX;
        #pragma unroll 2
        for (int kc = 0; kc < KX; kc += 32) {
            const int ko = kc + quad * 8;
            bf16x8 bh, bl;
            if constexpr (WSPLIT) {
                bh = ld8((const ushort*)Wih_a + woff + ko);
                bl = ld8((const ushort*)Wih_b + woff + ko);
            } else {
                split8((const float*)Wih_a + woff + ko, bh, bl);
            }
            bf16x8 ah, al;
            if constexpr (XSPLIT) {
                ah = ld8((const ushort*)x_p + arow * KX + ko);
                al = ld8(x_lo + arow * KX + ko);
            } else {
                split8((const float*)x_p + arow * KX + ko, ah, al);
            }
            acc0 = mfma16(ah, bh, acc0);
            acc1 = mfma16(ah, bl, acc1);
            acc2 = mfma16(al, bh, acc2);
        }
    }
    // gate exchange: Gt[col][local_row]; D: row=quad*4+r, col=l15
    #pragma unroll
    for (int r = 0; r < 4; r++)
        Gt[l15][(wave << 4) + quad * 4 + r] = acc0[r] + acc1[r] + acc2[r];
    __syncthreads();

    // cell update: thread -> (local batch row, h-local)
    const int bl_ = tid >> 2, hl = tid & 3;
    const int b = (blockIdx.y << 6) + bl_;
    const int hidx = h0 + hl;
    const float gi = Gt[hl][bl_]      + bih[hidx]          + bhh[hidx];
    const float gf = Gt[4 + hl][bl_]  + bih[H_ + hidx]     + bhh[H_ + hidx];
    const float gg = Gt[8 + hl][bl_]  + bih[2 * H_ + hidx] + bhh[2 * H_ + hidx];
    const float go = Gt[12 + hl][bl_] + bih[3 * H_ + hidx] + bhh[3 * H_ + hidx];
    const float ig = fast_sigmoid(gi), fg = fast_sigmoid(gf);
    const float gt = fast_tanh(gg),    og = fast_sigmoid(go);
    const float cold = c_in[b * H_ + hidx];
    const float cnew = fg * cold + ig * gt;
    const float hnew = og * fast_tanh(cnew);
    c_out[b * H_ + hidx] = cnew;
    const ushort hh = f2bf(hnew);
    h_out_hi[b * H_ + hidx] = hh;
    h_out_lo[b * H_ + hidx] = f2bf(hnew - bf2f(hh));
}

// ---- generic MFMA GEMM: C = act(A @ W^T + bias) ----------------------------
// grid (N/(16*NT), M/64). Wave = 1 M-tile(16 rows) x NT N-tiles.
// OM: 0=f32, 3=split bf16 (hi,lo), 4=fp16 dual-region (row<32768 -> out0)
template<bool A_LO, int NT, int OM, bool RELU, int K>
__global__ __launch_bounds__(256) void gemm_mfma(
    const ushort* __restrict__ Ahi, const ushort* __restrict__ Alo, int lda,
    const ushort* __restrict__ Whi, const ushort* __restrict__ Wlo,
    const float* __restrict__ bias,
    void* __restrict__ out0, void* __restrict__ out1, int ldc)
{
    const int tid = threadIdx.x;
    const int wave = tid >> 6, lane = tid & 63;
    const int quad = lane >> 4, l15 = lane & 15;
    const int colbase = (blockIdx.x * NT) << 4;
    const size_t row = ((size_t)blockIdx.y << 6) + (wave << 4) + l15;
    const size_t aoff = row * lda;

    f32x4 acc0[NT], acc1[NT], acc2[NT];
    #pragma unroll
    for (int nt = 0; nt < NT; nt++) {
        acc0[nt] = {0.f,0.f,0.f,0.f}; acc1[nt] = acc0[nt]; acc2[nt] = acc0[nt];
    }
    size_t woff[NT];
    #pragma unroll
    for (int nt = 0; nt < NT; nt++)
        woff[nt] = (size_t)(colbase + (nt << 4) + l15) * K;

    #pragma unroll 2
    for (int kc = 0; kc < K; kc += 32) {
        const int ko = kc + quad * 8;
        const bf16x8 ah = ld8(Ahi + aoff + ko);
        bf16x8 al;
        if (A_LO) al = ld8(Alo + aoff + ko);
        #pragma unroll
        for (int nt = 0; nt < NT; nt++) {
            const bf16x8 bh = ld8(Whi + woff[nt] + ko);
            const bf16x8 bl = ld8(Wlo + woff[nt] + ko);
            acc0[nt] = mfma16(ah, bh, acc0[nt]);
            acc1[nt] = mfma16(ah, bl, acc1[nt]);
            if (A_LO) acc2[nt] = mfma16(al, bh, acc2[nt]);
        }
    }
    const size_t orow0 = ((size_t)blockIdx.y << 6) + (wave << 4) + quad * 4;
    const size_t HALF_IDX = (size_t)32768 * 1024;   // P region boundary
    #pragma unroll
    for (int nt = 0; nt < NT; nt++) {
        const int col = colbase + (nt << 4) + l15;
        const float bv = bias ? bias[col] : 0.f;
        #pragma unroll
        for (int r = 0; r < 4; r++) {
            float v = acc0[nt][r] + acc1[nt][r] + (A_LO ? acc2[nt][r] : 0.f) + bv;
            if (RELU) v = fmaxf(v, 0.f);
            const size_t idx = (orow0 + r) * (size_t)ldc + col;
            if constexpr (OM == 0) {
                ((float*)out0)[idx] = v;
            } else if constexpr (OM == 3) {
                const ushort h = f2bf(v);
                ((ushort*)out0)[idx] = h;
                ((ushort*)out1)[idx] = f2bf(v - bf2f(h));
            } else {   // OM == 4: fp16 dual region
                if (idx < HALF_IDX) ((_Float16*)out0)[idx] = (_Float16)v;
                else                ((_Float16*)out1)[idx - HALF_IDX] = (_Float16)v;
            }
        }
    }
}

// ---- scores[b][t] = sum_h v[h]*tanh(q[b][h] + P[t][b][h]); P fp16 2-region -
__global__ __launch_bounds__(256) void attn_score_kernel(
    const float* __restrict__ q,
    const _Float16* __restrict__ P0, const _Float16* __restrict__ P1,
    const float* __restrict__ v, float* __restrict__ scores)
{
    const int wave = threadIdx.x >> 6, lane = threadIdx.x & 63;
    const int p = (blockIdx.x << 2) + wave;
    const int t = p >> 7, b = p & 127;
    const size_t base = (size_t)(t * B_ + b) * H_ + (lane << 4);
    const size_t HALF_IDX = (size_t)32768 * 1024;
    const _Float16* pp = (base < HALF_IDX) ? (P0 + base) : (P1 + (base - HALF_IDX));

    const half8 u0 = *(const half8*)(const void*)pp;
    const half8 u1 = *(const half8*)(const void*)(pp + 8);
    float pv[16];
    #pragma unroll
    for (int j = 0; j < 8; j++) { pv[j] = (float)u0[j]; pv[8 + j] = (float)u1[j]; }

    const float* qp = q + b * H_ + (lane << 4);
    const float* vp = v + (lane << 4);
    float sum = 0.f;
    #pragma unroll
    for (int j0 = 0; j0 < 16; j0 += 4) {
        const float4 qv = *(const float4*)(qp + j0);
        const float4 vv = *(const float4*)(vp + j0);
        sum += vv.x * fast_tanh(qv.x + pv[j0 + 0]);
        sum += vv.y * fast_tanh(qv.y + pv[j0 + 1]);
        sum += vv.z * fast_tanh(qv.z + pv[j0 + 2]);
        sum += vv.w * fast_tanh(qv.w + pv[j0 + 3]);
    }
    #pragma unroll
    for (int off = 32; off; off >>= 1) sum += __shfl_down(sum, off);
    if (lane == 0) scores[b * T_ + t] = sum;
}

// ---- softmax over t, in place ----------------------------------------------
__global__ __launch_bounds__(256) void softmax_kernel(float* __restrict__ scores)
{
    __shared__ float red[256];
    const int b = blockIdx.x, tid = threadIdx.x;
    const float s0 = scores[b * T_ + tid];
    const float s1 = scores[b * T_ + tid + 256];
    red[tid] = fmaxf(s0, s1);
    __syncthreads();
    for (int off = 128; off; off >>= 1) {
        if (tid < off) red[tid] = fmaxf(red[tid], red[tid + off]);
        __syncthreads();
    }
    const float mx = red[0];
    __syncthreads();
    const float e0 = __expf(s0 - mx), e1 = __expf(s1 - mx);
    red[tid] = e0 + e1;
    __syncthreads();
    for (int off = 128; off; off >>= 1) {
        if (tid < off) red[tid] += red[tid + off];
        __syncthreads();
    }
    const float inv = 1.f / red[0];
    scores[b * T_ + tid] = e0 * inv;
    scores[b * T_ + tid + 256] = e1 * inv;
}

// ---- context[b][h] = sum_t wts[b][t]*ctx[t][b][h]; out = split pairs -------
__global__ __launch_bounds__(256) void attn_context_kernel(
    const float* __restrict__ wts, const ushort* __restrict__ ctx,
    ushort* __restrict__ chi, ushort* __restrict__ clo)
{
    const int u = blockIdx.x * 256 + threadIdx.x;
    const int b = u >> 9;
    const int h2 = (u & 511) << 1;
    const float* wb = wts + b * T_;
    const ushort* cp = ctx + ((size_t)b * H_ + h2);
    float a0 = 0.f, a1 = 0.f;
    #pragma unroll 4
    for (int t = 0; t < T_; t++) {
        const float w = wb[t];
        const ushort2 uu = *(const ushort2*)(cp + (size_t)t * (B_ * H_));
        a0 += w * bf2f(uu.x);
        a1 += w * bf2f(uu.y);
    }
    const size_t i0 = (size_t)b * H_ + h2;
    const ushort h0 = f2bf(a0), h1 = f2bf(a1);
    chi[i0] = h0;     clo[i0] = f2bf(a0 - bf2f(h0));
    chi[i0 + 1] = h1; clo[i0 + 1] = f2bf(a1 - bf2f(h1));
}

// ---------------------------------------------------------------------------
extern "C" void kernel_launch(void* const* d_in, const int* in_sizes, int n_in,
                              void* d_out, int out_size, void* d_ws, size_t ws_size,
                              hipStream_t stream)
{
    const float* input_seq = (const float*)d_in[0];
    const float* W_ih_enc  = (const float*)d_in[1];
    const float* W_hh_enc  = (const float*)d_in[2];
    const float* b_ih_enc  = (const float*)d_in[3];
    const float* b_hh_enc  = (const float*)d_in[4];
    const float* W_attn    = (const float*)d_in[5];
    const float* b_attn    = (const float*)d_in[6];
    const float* v         = (const float*)d_in[7];
    const float* W_ih_dec  = (const float*)d_in[8];
    const float* W_hh_dec  = (const float*)d_in[9];
    const float* b_ih_dec  = (const float*)d_in[10];
    const float* b_hh_dec  = (const float*)d_in[11];
    const float* W_dec     = (const float*)d_in[12];
    const float* b_dec     = (const float*)d_in[13];
    const float* W_out     = (const float*)d_in[14];
    const float* b_out     = (const float*)d_in[15];
    float* out = (float*)d_out;
    const int LEN = out_size / (B_ * O_);   // 30
    const int BH = B_ * H_;

    char* ws = (char*)d_ws;
    size_t off = 0;
    auto aus = [&](size_t n) { ushort* p = (ushort*)(ws + off); off += n * 2; return p; };
    auto af  = [&](size_t n) { float*  p = (float*) (ws + off); off += n * 4; return p; };

    // pre-split weights (hot / MFMA-consumed). Decoder LSTM W split on the fly.
    ushort* WhhE_h = aus((size_t)4*H_*H_); ushort* WhhE_l = aus((size_t)4*H_*H_);
    ushort* WihE_h = aus((size_t)4*H_*I_); ushort* WihE_l = aus((size_t)4*H_*I_);
    ushort* Wh_h   = aus((size_t)H_*H_);   ushort* Wh_l   = aus((size_t)H_*H_);
    ushort* Wc_h   = aus((size_t)H_*H_);   ushort* Wc_l   = aus((size_t)H_*H_);
    ushort* Wdec_h = aus((size_t)H_*H_);   ushort* Wdec_l = aus((size_t)H_*H_);
    ushort* Wout_h = aus((size_t)O_*H_);   ushort* Wout_l = aus((size_t)O_*H_);

    ushort* ctx_seq = aus((size_t)T_ * BH);          // encoder h_hi history
    ushort* hzero   = aus(BH);
    ushort* enc_lo0 = aus(BH); ushort* enc_lo1 = aus(BH);
    ushort* hd_hi0  = aus(BH); ushort* hd_hi1  = aus(BH);
    ushort* hd_lo0  = aus(BH); ushort* hd_lo1  = aus(BH);
    ushort* ctx_hi  = aus(BH); ushort* ctx_lo  = aus(BH);
    ushort* d1_hi   = aus(BH); ushort* d1_lo   = aus(BH);
    float*  cbuf    = af(BH);
    float*  qbuf    = af(BH);
    float*  scores  = af(B_ * T_);
    unsigned* barbuf = (unsigned*)(ws + off); off += 256;   // grid-barrier state

    // P (fp16, T*B*H = 134.2MB) in two 67.1MB halves.
    const size_t P_HALF = (size_t)(T_ / 2) * BH * 2;   // 67,108,864
    _Float16 *P0, *P1;
    if (ws_size >= off + 2 * P_HALF) {        // layout A: both halves in ws
        P0 = (_Float16*)(ws + off);
        P1 = (_Float16*)(ws + off + P_HALF);
    } else {                                   // layout B: half 1 aliases input_seq
        P0 = (_Float16*)const_cast<float*>(input_seq);   // dead after encoder
        P1 = (_Float16*)(ws + off);            // off ~173MB + 67.1MB <= budget
    }

    // ---- weight split pre-pass ----
    auto spl = [&](const float* src, int srcld, int coloff, ushort* hi, ushort* lo,
                   int R, int K) {
        split_w<<<dim3(K / 256, R), 256, 0, stream>>>(src, srcld, coloff, hi, lo, K);
    };
    spl(W_hh_enc, H_,     0,  WhhE_h, WhhE_l, 4 * H_, H_);
    spl(W_ih_enc, I_,     0,  WihE_h, WihE_l, 4 * H_, I_);
    spl(W_attn,   2 * H_, 0,  Wh_h,   Wh_l,   H_,     H_);
    spl(W_attn,   2 * H_, H_, Wc_h,   Wc_l,   H_,     H_);
    spl(W_dec,    H_,     0,  Wdec_h, Wdec_l, H_,     H_);
    spl(W_out,    H_,     0,  Wout_h, Wout_l, O_,     H_);

    hipMemsetAsync(hzero,   0, (size_t)BH * 2, stream);
    hipMemsetAsync(enc_lo0, 0, (size_t)BH * 2, stream);
    hipMemsetAsync(barbuf,  0, 256, stream);

    // ---- encoder: ONE persistent kernel, 512 steps with internal grid
    //      barriers. 256 blocks (1/CU -> co-residency guaranteed). ----
    enc_persistent<<<dim3(H_ / 4), 512, ENC_SMEM_BYTES, stream>>>(
        input_seq, WhhE_h, WhhE_l, WihE_h, WihE_l, b_ih_enc, b_hh_enc,
        hzero, ctx_seq, enc_lo0, enc_lo1, barbuf);
    // enc final: hi = ctx_seq[511], lo = enc_lo0

    // ---- P = ctx_seq @ W_c^T + b_attn  (fp16, dual region; may overwrite
    //      input_seq — safe: encoder already consumed it) ----
    gemm_mfma<false, 8, 4, false, H_><<<dim3(8, (T_ * B_) / 64), 256, 0, stream>>>(
        ctx_seq, nullptr, H_, Wc_h, Wc_l, b_attn, P0, P1, H_);

    // ---- decoder ----
    hipMemsetAsync(cbuf, 0, (size_t)BH * 4, stream);
    ushort* dhh[2] = {hd_hi0, hd_hi1};
    ushort* dhl[2] = {hd_lo0, hd_lo1};
    for (int s = 0; s < LEN; s++) {
        const ushort* hi_in = (s == 0) ? ctx_seq + (size_t)(T_ - 1) * BH : dhh[s & 1];
        const ushort* lo_in = (s == 0) ? enc_lo0 : dhl[s & 1];

        // q = h @ W_h^T (bias folded into P)
        gemm_mfma<true, 1, 0, false, H_><<<dim3(H_ / 16, 2), 256, 0, stream>>>(
            hi_in, lo_in, H_, Wh_h, Wh_l, nullptr, qbuf, nullptr, H_);
        attn_score_kernel<<<T_ * B_ / 4, 256, 0, stream>>>(qbuf, P0, P1, v, scores);
        softmax_kernel<<<B_, 256, 0, stream>>>(scores);
        attn_context_kernel<<<BH / 512, 256, 0, stream>>>(scores, ctx_seq, ctx_hi, ctx_lo);
        // decoder LSTM cell (x = context split; weights split on the fly)
        lstm_mfma<false, true, H_><<<dim3(H_ / 4, 2), 256, 0, stream>>>(
            hi_in, lo_in, (const void*)ctx_hi, ctx_lo,
            W_hh_dec, nullptr, W_ih_dec, nullptr, b_ih_dec, b_hh_dec,
            cbuf, cbuf, dhh[(s + 1) & 1], dhl[(s + 1) & 1]);
        // d1 = relu(h @ W_dec^T + b_dec) -> split
        gemm_mfma<true, 1, 3, true, H_><<<dim3(H_ / 16, 2), 256, 0, stream>>>(
            dhh[(s + 1) & 1], dhl[(s + 1) & 1], H_, Wdec_h, Wdec_l, b_dec,
            d1_hi, d1_lo, H_);
        // out = d1 @ W_out^T + b_out
        gemm_mfma<true, 1, 0, false, H_><<<dim3(O_ / 16, 2), 256, 0, stream>>>(
            d1_hi, d1_lo, H_, Wout_h, Wout_l, b_out,
            out + (size_t)s * B_ * O_, nullptr, O_);
    }
    (void)in_sizes; (void)n_in;
}

// Round 2
// 29135.938 us; speedup vs baseline: 1.0635x; 1.0635x over previous
//
#include <hip/hip_runtime.h>
#include <hip/hip_bf16.h>
#include <type_traits>

// ---------------------------------------------------------------------------
// Seq2SeqAttention R6: persistent encoder, fence-free coherent h-exchange.
//   R5 post-mortem: __threadfence() in the grid barrier = buffer_wbl2/inv sc1
//   (FULL per-XCD L2 writeback+invalidate) per block per step -> all caches
//   wiped 256x511x2 times -> every load pays IC latency -> 42us/step.
//   R6: NO fences anywhere. Cross-step h (hi+lo) exchanged through a 2-deep
//   ring written/read with RELAXED AGENT-scope atomics (= plain global ops
//   with sc1 coherence bits: point of coherence is the Infinity Cache, no
//   cache invalidation, compiler-pipelined). ctx_seq keeps plain stores
//   (read only after kernel end). Barrier: monotonic arrival count, relaxed.
// MFMA 16x16x32 bf16 layouts (m89/m91-verified): A[m=lane&15][k=quad*8+j],
// B[k=quad*8+j][n=lane&15], D col=lane&15 row=quad*4+reg.
// ---------------------------------------------------------------------------

static constexpr int T_ = 512, B_ = 128, I_ = 256, H_ = 1024, O_ = 256;

typedef unsigned short ushort;
typedef unsigned long long u64;
typedef __attribute__((ext_vector_type(8))) short bf16x8;
typedef __attribute__((ext_vector_type(4))) float f32x4;
typedef __attribute__((ext_vector_type(8))) unsigned short ushort8_t;
typedef __attribute__((ext_vector_type(8))) _Float16 half8;

__device__ __forceinline__ float bf2f(ushort u) {
    union { unsigned i; float f; } cv; cv.i = ((unsigned)u) << 16; return cv.f;
}
__device__ __forceinline__ ushort f2bf(float f) {   // RNE
    union { float f; unsigned u; } c; c.f = f;
    unsigned r = c.u + 0x7FFFu + ((c.u >> 16) & 1u);
    return (ushort)(r >> 16);
}
__device__ __forceinline__ float fast_sigmoid(float x) { return 1.f / (1.f + __expf(-x)); }
__device__ __forceinline__ float fast_tanh(float x) {
    float ax = fabsf(x);
    float e = __expf(-2.f * ax);
    float t = (1.f - e) / (1.f + e);
    return copysignf(t, x);
}
__device__ __forceinline__ f32x4 mfma16(bf16x8 a, bf16x8 b, f32x4 c) {
    return __builtin_amdgcn_mfma_f32_16x16x32_bf16(a, b, c, 0, 0, 0);
}
__device__ __forceinline__ bf16x8 ld8(const ushort* p) { return *(const bf16x8*)(const void*)p; }

// coherent (agent-scope, relaxed) 16B fragment load: 2x 8B atomic loads.
// Compiles to global_load_dwordx2 with sc-coherence bits: bypasses stale
// L1/L2 copies, reads the IC point-of-coherence, fully pipelined.
__device__ __forceinline__ bf16x8 ld8_cc(const ushort* p) {
    union { u64 q[2]; bf16x8 v; } u;
    u.q[0] = __hip_atomic_load((const u64*)(const void*)p, __ATOMIC_RELAXED,
                               __HIP_MEMORY_SCOPE_AGENT);
    u.q[1] = __hip_atomic_load((const u64*)(const void*)p + 1, __ATOMIC_RELAXED,
                               __HIP_MEMORY_SCOPE_AGENT);
    return u.v;
}

// ---- split 8 fp32 into bf16 hi/lo fragments --------------------------------
__device__ __forceinline__ void split8(const float* p, bf16x8& hi, bf16x8& lo) {
    #pragma unroll
    for (int j = 0; j < 8; j++) {
        const float f = p[j];
        const ushort h = f2bf(f);
        hi[j] = (short)h;
        lo[j] = (short)f2bf(f - bf2f(h));
    }
}

// ---- weight split pre-pass -------------------------------------------------
__global__ __launch_bounds__(256) void split_w(
    const float* __restrict__ src, int srcld, int coloff,
    ushort* __restrict__ hi, ushort* __restrict__ lo, int K)
{
    const int k = blockIdx.x * 256 + threadIdx.x;
    const int r = blockIdx.y;
    const float f = src[(size_t)r * srcld + coloff + k];
    const ushort h = f2bf(f);
    hi[(size_t)r * K + k] = h;
    lo[(size_t)r * K + k] = f2bf(f - bf2f(h));
}

// ---------------------------------------------------------------------------
// Persistent encoder: 256 blocks (1/CU), 512 threads (8 waves). Block owns
// 4 h-values (16 gate-cols) x all 128 batch rows; wave w = row-tile w*16.
// LDS: Whh hi/lo [32 iters][64 lanes][8] + Wih hi/lo [8][64][8] + Gt[16][132].
// h ring: Hhi/Hlo[2] via relaxed agent atomics; grid barrier fence-free.
// ---------------------------------------------------------------------------
#define ENC_SMEM_BYTES (32*64*8*2*2 + 8*64*8*2*2 + 16*132*4)   // 90368

__global__ __launch_bounds__(512) void enc_persistent(
    const float* __restrict__ input_seq,
    const ushort* __restrict__ WhhE_h, const ushort* __restrict__ WhhE_l,
    const ushort* __restrict__ WihE_h, const ushort* __restrict__ WihE_l,
    const float* __restrict__ bih, const float* __restrict__ bhh,
    ushort* __restrict__ ctx_seq,
    ushort* __restrict__ Hhi0, ushort* __restrict__ Hhi1,
    ushort* __restrict__ Hlo0, ushort* __restrict__ Hlo1,
    unsigned* __restrict__ bar)     // bar[0]=cumulative arrivals, bar[1]=released step
{
    extern __shared__ __align__(16) char smem[];
    ushort* LWh = (ushort*)smem;                 // Whh hi  [32][64][8]
    ushort* LWl = LWh + 32 * 64 * 8;             // Whh lo
    ushort* LIh = LWl + 32 * 64 * 8;             // Wih hi  [8][64][8]
    ushort* LIl = LIh + 8 * 64 * 8;              // Wih lo
    float*  Gt  = (float*)(LIl + 8 * 64 * 8);    // [16 cols][132]

    const int tid  = threadIdx.x;
    const int wave = tid >> 6, lane = tid & 63;
    const int quad = lane >> 4, l15 = lane & 15;
    const int h0   = blockIdx.x << 2;
    const int wr   = ((l15 >> 2) * H_) + h0 + (l15 & 3);   // gate*H + h row of W

    // ---- stage weights into LDS (lane-major fragments; done once) ----
    {
        const size_t woff = (size_t)wr * H_;
        #pragma unroll
        for (int ii = 0; ii < 4; ii++) {
            const int i   = wave + (ii << 3);          // K-iter index 0..31
            const int src = (i << 5) + (quad << 3);
            *(bf16x8*)(LWh + ((i << 6) + lane) * 8) = ld8(WhhE_h + woff + src);
            *(bf16x8*)(LWl + ((i << 6) + lane) * 8) = ld8(WhhE_l + woff + src);
        }
        const size_t ioff = (size_t)wr * I_;
        const int src2 = (wave << 5) + (quad << 3);    // K-iter index = wave (0..7)
        *(bf16x8*)(LIh + ((wave << 6) + lane) * 8) = ld8(WihE_h + ioff + src2);
        *(bf16x8*)(LIl + ((wave << 6) + lane) * 8) = ld8(WihE_l + ioff + src2);
    }

    // per-thread cell-update mapping + persistent state
    const int bl_  = tid >> 2, hl = tid & 3;
    const int hidx = h0 + hl;
    const float bs0 = bih[hidx]           + bhh[hidx];
    const float bs1 = bih[H_ + hidx]      + bhh[H_ + hidx];
    const float bs2 = bih[2 * H_ + hidx]  + bhh[2 * H_ + hidx];
    const float bs3 = bih[3 * H_ + hidx]  + bhh[3 * H_ + hidx];
    float c_reg = 0.f;
    unsigned genv = 0;
    __syncthreads();

    const size_t arow = (size_t)((wave << 4) + l15);   // batch row for MFMA A
    const size_t aoff = arow * H_;
    const size_t xoff = arow * I_;

    for (int t = 0; t < T_; t++) {
        // ring: h_{t-1} in index (t+1)&1, h_t written to index t&1
        const ushort* Hp_hi = (t & 1) ? Hhi0 : Hhi1;
        const ushort* Hp_lo = (t & 1) ? Hlo0 : Hlo1;
        ushort*       Hc_hi = (t & 1) ? Hhi1 : Hhi0;
        ushort*       Hc_lo = (t & 1) ? Hlo1 : Hlo0;
        const float*  xs    = input_seq + (size_t)t * (B_ * I_);

        f32x4 acc0 = {0.f, 0.f, 0.f, 0.f}, acc1 = acc0, acc2 = acc0;
        // segment 1: h @ Whh^T (weights from LDS, A via coherent IC loads)
        #pragma unroll 8
        for (int kc = 0; kc < H_; kc += 32) {
            const int i = kc >> 5;
            const bf16x8 bh = *(const bf16x8*)(LWh + ((i << 6) + lane) * 8);
            const bf16x8 bl = *(const bf16x8*)(LWl + ((i << 6) + lane) * 8);
            const bf16x8 ah = ld8_cc(Hp_hi + aoff + kc + (quad << 3));
            const bf16x8 al = ld8_cc(Hp_lo + aoff + kc + (quad << 3));
            acc0 = mfma16(ah, bh, acc0);
            acc1 = mfma16(ah, bl, acc1);
            acc2 = mfma16(al, bh, acc2);
        }
        // segment 2: x @ Wih^T (x fp32 read-only, normal cached loads)
        #pragma unroll
        for (int kc = 0; kc < I_; kc += 32) {
            const int i = kc >> 5;
            const bf16x8 bh = *(const bf16x8*)(LIh + ((i << 6) + lane) * 8);
            const bf16x8 bl = *(const bf16x8*)(LIl + ((i << 6) + lane) * 8);
            bf16x8 ah, al;
            split8(xs + xoff + kc + (quad << 3), ah, al);
            acc0 = mfma16(ah, bh, acc0);
            acc1 = mfma16(ah, bl, acc1);
            acc2 = mfma16(al, bh, acc2);
        }
        // gate exchange: Gt[col][row]; D: row=quad*4+r, col=l15
        #pragma unroll
        for (int r = 0; r < 4; r++)
            Gt[l15 * 132 + (wave << 4) + (quad << 2) + r] = acc0[r] + acc1[r] + acc2[r];
        __syncthreads();

        // cell update (thread -> (batch row bl_, h-local hl)); c in register
        const float gi = Gt[hl * 132 + bl_]        + bs0;
        const float gf = Gt[(4 + hl) * 132 + bl_]  + bs1;
        const float gg = Gt[(8 + hl) * 132 + bl_]  + bs2;
        const float go = Gt[(12 + hl) * 132 + bl_] + bs3;
        const float ig = fast_sigmoid(gi), fg = fast_sigmoid(gf);
        const float gtv = fast_tanh(gg),   og = fast_sigmoid(go);
        c_reg = fg * c_reg + ig * gtv;
        const float hnew = og * fast_tanh(c_reg);
        const size_t oidx = (size_t)bl_ * H_ + hidx;
        const ushort hh  = f2bf(hnew);
        const ushort hlo = f2bf(hnew - bf2f(hh));
        ctx_seq[(size_t)t * (B_ * H_) + oidx] = hh;    // plain (post-kernel use)

        // coherent ring store: pair-pack 2B values into 4B atomic stores
        const unsigned hi_up = __shfl_down((unsigned)hh, 1);
        const unsigned lo_up = __shfl_down((unsigned)hlo, 1);
        if (!(tid & 1)) {
            __hip_atomic_store((unsigned*)(void*)&Hc_hi[oidx],
                               (unsigned)hh | (hi_up << 16),
                               __ATOMIC_RELAXED, __HIP_MEMORY_SCOPE_AGENT);
            __hip_atomic_store((unsigned*)(void*)&Hc_lo[oidx],
                               (unsigned)hlo | (lo_up << 16),
                               __ATOMIC_RELAXED, __HIP_MEMORY_SCOPE_AGENT);
        }

        // fence-free grid barrier (monotonic arrivals; no reset, no race).
        // __syncthreads drains each wave's stores (vmcnt) before arrival;
        // sc-flagged stores are IC-visible once retired.
        if (t != T_ - 1) {
            __syncthreads();
            if (tid == 0) {
                const unsigned arrived =
                    __hip_atomic_fetch_add(&bar[0], 1u, __ATOMIC_RELAXED,
                                           __HIP_MEMORY_SCOPE_AGENT) + 1;
                const unsigned target = ++genv;
                if (arrived == target * 256u) {
                    __hip_atomic_store(&bar[1], target, __ATOMIC_RELAXED,
                                       __HIP_MEMORY_SCOPE_AGENT);
                } else {
                    while (__hip_atomic_load(&bar[1], __ATOMIC_RELAXED,
                                             __HIP_MEMORY_SCOPE_AGENT) < target)
                        __builtin_amdgcn_s_sleep(2);
                }
            }
            __syncthreads();
        }
    }
}

// ---- fused LSTM step (MFMA). Block: 64 batch rows x 16 gate-cols. ----------
// (decoder only now) grid (H/4 = 256 colgroups, 2 row-halves).
template<bool WSPLIT, bool XSPLIT, int KX>
__global__ __launch_bounds__(256) void lstm_mfma(
    const ushort* __restrict__ h_hi, const ushort* __restrict__ h_lo,
    const void* __restrict__ x_p, const ushort* __restrict__ x_lo,
    const void* __restrict__ Whh_a, const void* __restrict__ Whh_b,
    const void* __restrict__ Wih_a, const void* __restrict__ Wih_b,
    const float* __restrict__ bih, const float* __restrict__ bhh,
    const float* __restrict__ c_in, float* __restrict__ c_out,
    ushort* __restrict__ h_out_hi, ushort* __restrict__ h_out_lo)
{
    __shared__ float Gt[16][65];
    const int tid = threadIdx.x;
    const int wave = tid >> 6, lane = tid & 63;
    const int quad = lane >> 4, l15 = lane & 15;
    const int h0 = blockIdx.x << 2;
    const int mbase = (blockIdx.y << 6) + (wave << 4);
    const size_t arow = (size_t)(mbase + l15);
    const int wr = ((l15 >> 2) * H_) + h0 + (l15 & 3);   // gate*H + h index

    f32x4 acc0 = {0.f,0.f,0.f,0.f}, acc1 = acc0, acc2 = acc0;

    // segment 1: h @ Whh^T, K = 1024, A split (hi+lo)
    {
        const size_t aoff = arow * H_;
        const size_t woff = (size_t)wr * H_;
        #pragma unroll 4
        for (int kc = 0; kc < H_; kc += 32) {
            const int ko = kc + quad * 8;
            bf16x8 bh, bl;
            if constexpr (WSPLIT) {
                bh = ld8((const ushort*)Whh_a + woff + ko);
                bl = ld8((const ushort*)Whh_b + woff + ko);
            } else {
                split8((const float*)Whh_a + woff + ko, bh, bl);
            }
            const bf16x8 ah = ld8(h_hi + aoff + ko);
            const bf16x8 al = ld8(h_lo + aoff + ko);
            acc0 = mfma16(ah, bh, acc0);
            acc1 = mfma16(ah, bl, acc1);
            acc2 = mfma16(al, bh, acc2);
        }
    }
    // segment 2: x @ Wih^T, K = KX
    {
        const size_t woff = (size_t)wr * KX;
        #pragma unroll 2
        for (int kc = 0; kc < KX; kc += 32) {
            const int ko = kc + quad * 8;
            bf16x8 bh, bl;
            if constexpr (WSPLIT) {
                bh = ld8((const ushort*)Wih_a + woff + ko);
                bl = ld8((const ushort*)Wih_b + woff + ko);
            } else {
                split8((const float*)Wih_a + woff + ko, bh, bl);
            }
            bf16x8 ah, al;
            if constexpr (XSPLIT) {
                ah = ld8((const ushort*)x_p + arow * KX + ko);
                al = ld8(x_lo + arow * KX + ko);
            } else {
                split8((const float*)x_p + arow * KX + ko, ah, al);
            }
            acc0 = mfma16(ah, bh, acc0);
            acc1 = mfma16(ah, bl, acc1);
            acc2 = mfma16(al, bh, acc2);
        }
    }
    // gate exchange: Gt[col][local_row]; D: row=quad*4+r, col=l15
    #pragma unroll
    for (int r = 0; r < 4; r++)
        Gt[l15][(wave << 4) + quad * 4 + r] = acc0[r] + acc1[r] + acc2[r];
    __syncthreads();

    // cell update: thread -> (local batch row, h-local)
    const int bl_ = tid >> 2, hl = tid & 3;
    const int b = (blockIdx.y << 6) + bl_;
    const int hidx = h0 + hl;
    const float gi = Gt[hl][bl_]      + bih[hidx]          + bhh[hidx];
    const float gf = Gt[4 + hl][bl_]  + bih[H_ + hidx]     + bhh[H_ + hidx];
    const float gg = Gt[8 + hl][bl_]  + bih[2 * H_ + hidx] + bhh[2 * H_ + hidx];
    const float go = Gt[12 + hl][bl_] + bih[3 * H_ + hidx] + bhh[3 * H_ + hidx];
    const float ig = fast_sigmoid(gi), fg = fast_sigmoid(gf);
    const float gt = fast_tanh(gg),    og = fast_sigmoid(go);
    const float cold = c_in[b * H_ + hidx];
    const float cnew = fg * cold + ig * gt;
    const float hnew = og * fast_tanh(cnew);
    c_out[b * H_ + hidx] = cnew;
    const ushort hh = f2bf(hnew);
    h_out_hi[b * H_ + hidx] = hh;
    h_out_lo[b * H_ + hidx] = f2bf(hnew - bf2f(hh));
}

// ---- generic MFMA GEMM: C = act(A @ W^T + bias) ----------------------------
// grid (N/(16*NT), M/64). Wave = 1 M-tile(16 rows) x NT N-tiles.
// OM: 0=f32, 3=split bf16 (hi,lo), 4=fp16 dual-region (row<32768 -> out0)
template<bool A_LO, int NT, int OM, bool RELU, int K>
__global__ __launch_bounds__(256) void gemm_mfma(
    const ushort* __restrict__ Ahi, const ushort* __restrict__ Alo, int lda,
    const ushort* __restrict__ Whi, const ushort* __restrict__ Wlo,
    const float* __restrict__ bias,
    void* __restrict__ out0, void* __restrict__ out1, int ldc)
{
    const int tid = threadIdx.x;
    const int wave = tid >> 6, lane = tid & 63;
    const int quad = lane >> 4, l15 = lane & 15;
    const int colbase = (blockIdx.x * NT) << 4;
    const size_t row = ((size_t)blockIdx.y << 6) + (wave << 4) + l15;
    const size_t aoff = row * lda;

    f32x4 acc0[NT], acc1[NT], acc2[NT];
    #pragma unroll
    for (int nt = 0; nt < NT; nt++) {
        acc0[nt] = {0.f,0.f,0.f,0.f}; acc1[nt] = acc0[nt]; acc2[nt] = acc0[nt];
    }
    size_t woff[NT];
    #pragma unroll
    for (int nt = 0; nt < NT; nt++)
        woff[nt] = (size_t)(colbase + (nt << 4) + l15) * K;

    #pragma unroll 2
    for (int kc = 0; kc < K; kc += 32) {
        const int ko = kc + quad * 8;
        const bf16x8 ah = ld8(Ahi + aoff + ko);
        bf16x8 al;
        if (A_LO) al = ld8(Alo + aoff + ko);
        #pragma unroll
        for (int nt = 0; nt < NT; nt++) {
            const bf16x8 bh = ld8(Whi + woff[nt] + ko);
            const bf16x8 bl = ld8(Wlo + woff[nt] + ko);
            acc0[nt] = mfma16(ah, bh, acc0[nt]);
            acc1[nt] = mfma16(ah, bl, acc1[nt]);
            if (A_LO) acc2[nt] = mfma16(al, bh, acc2[nt]);
        }
    }
    const size_t orow0 = ((size_t)blockIdx.y << 6) + (wave << 4) + quad * 4;
    const size_t HALF_IDX = (size_t)32768 * 1024;   // P region boundary
    #pragma unroll
    for (int nt = 0; nt < NT; nt++) {
        const int col = colbase + (nt << 4) + l15;
        const float bv = bias ? bias[col] : 0.f;
        #pragma unroll
        for (int r = 0; r < 4; r++) {
            float v = acc0[nt][r] + acc1[nt][r] + (A_LO ? acc2[nt][r] : 0.f) + bv;
            if (RELU) v = fmaxf(v, 0.f);
            const size_t idx = (orow0 + r) * (size_t)ldc + col;
            if constexpr (OM == 0) {
                ((float*)out0)[idx] = v;
            } else if constexpr (OM == 3) {
                const ushort h = f2bf(v);
                ((ushort*)out0)[idx] = h;
                ((ushort*)out1)[idx] = f2bf(v - bf2f(h));
            } else {   // OM == 4: fp16 dual region
                if (idx < HALF_IDX) ((_Float16*)out0)[idx] = (_Float16)v;
                else                ((_Float16*)out1)[idx - HALF_IDX] = (_Float16)v;
            }
        }
    }
}

// ---- scores[b][t] = sum_h v[h]*tanh(q[b][h] + P[t][b][h]); P fp16 2-region -
__global__ __launch_bounds__(256) void attn_score_kernel(
    const float* __restrict__ q,
    const _Float16* __restrict__ P0, const _Float16* __restrict__ P1,
    const float* __restrict__ v, float* __restrict__ scores)
{
    const int wave = threadIdx.x >> 6, lane = threadIdx.x & 63;
    const int p = (blockIdx.x << 2) + wave;
    const int t = p >> 7, b = p & 127;
    const size_t base = (size_t)(t * B_ + b) * H_ + (lane << 4);
    const size_t HALF_IDX = (size_t)32768 * 1024;
    const _Float16* pp = (base < HALF_IDX) ? (P0 + base) : (P1 + (base - HALF_IDX));

    const half8 u0 = *(const half8*)(const void*)pp;
    const half8 u1 = *(const half8*)(const void*)(pp + 8);
    float pv[16];
    #pragma unroll
    for (int j = 0; j < 8; j++) { pv[j] = (float)u0[j]; pv[8 + j] = (float)u1[j]; }

    const float* qp = q + b * H_ + (lane << 4);
    const float* vp = v + (lane << 4);
    float sum = 0.f;
    #pragma unroll
    for (int j0 = 0; j0 < 16; j0 += 4) {
        const float4 qv = *(const float4*)(qp + j0);
        const float4 vv = *(const float4*)(vp + j0);
        sum += vv.x * fast_tanh(qv.x + pv[j0 + 0]);
        sum += vv.y * fast_tanh(qv.y + pv[j0 + 1]);
        sum += vv.z * fast_tanh(qv.z + pv[j0 + 2]);
        sum += vv.w * fast_tanh(qv.w + pv[j0 + 3]);
    }
    #pragma unroll
    for (int off = 32; off; off >>= 1) sum += __shfl_down(sum, off);
    if (lane == 0) scores[b * T_ + t] = sum;
}

// ---- softmax over t, in place ----------------------------------------------
__global__ __launch_bounds__(256) void softmax_kernel(float* __restrict__ scores)
{
    __shared__ float red[256];
    const int b = blockIdx.x, tid = threadIdx.x;
    const float s0 = scores[b * T_ + tid];
    const float s1 = scores[b * T_ + tid + 256];
    red[tid] = fmaxf(s0, s1);
    __syncthreads();
    for (int off = 128; off; off >>= 1) {
        if (tid < off) red[tid] = fmaxf(red[tid], red[tid + off]);
        __syncthreads();
    }
    const float mx = red[0];
    __syncthreads();
    const float e0 = __expf(s0 - mx), e1 = __expf(s1 - mx);
    red[tid] = e0 + e1;
    __syncthreads();
    for (int off = 128; off; off >>= 1) {
        if (tid < off) red[tid] += red[tid + off];
        __syncthreads();
    }
    const float inv = 1.f / red[0];
    scores[b * T_ + tid] = e0 * inv;
    scores[b * T_ + tid + 256] = e1 * inv;
}

// ---- context[b][h] = sum_t wts[b][t]*ctx[t][b][h]; out = split pairs -------
__global__ __launch_bounds__(256) void attn_context_kernel(
    const float* __restrict__ wts, const ushort* __restrict__ ctx,
    ushort* __restrict__ chi, ushort* __restrict__ clo)
{
    const int u = blockIdx.x * 256 + threadIdx.x;
    const int b = u >> 9;
    const int h2 = (u & 511) << 1;
    const float* wb = wts + b * T_;
    const ushort* cp = ctx + ((size_t)b * H_ + h2);
    float a0 = 0.f, a1 = 0.f;
    #pragma unroll 4
    for (int t = 0; t < T_; t++) {
        const float w = wb[t];
        const ushort2 uu = *(const ushort2*)(cp + (size_t)t * (B_ * H_));
        a0 += w * bf2f(uu.x);
        a1 += w * bf2f(uu.y);
    }
    const size_t i0 = (size_t)b * H_ + h2;
    const ushort h0 = f2bf(a0), h1 = f2bf(a1);
    chi[i0] = h0;     clo[i0] = f2bf(a0 - bf2f(h0));
    chi[i0 + 1] = h1; clo[i0 + 1] = f2bf(a1 - bf2f(h1));
}

// ---------------------------------------------------------------------------
extern "C" void kernel_launch(void* const* d_in, const int* in_sizes, int n_in,
                              void* d_out, int out_size, void* d_ws, size_t ws_size,
                              hipStream_t stream)
{
    const float* input_seq = (const float*)d_in[0];
    const float* W_ih_enc  = (const float*)d_in[1];
    const float* W_hh_enc  = (const float*)d_in[2];
    const float* b_ih_enc  = (const float*)d_in[3];
    const float* b_hh_enc  = (const float*)d_in[4];
    const float* W_attn    = (const float*)d_in[5];
    const float* b_attn    = (const float*)d_in[6];
    const float* v         = (const float*)d_in[7];
    const float* W_ih_dec  = (const float*)d_in[8];
    const float* W_hh_dec  = (const float*)d_in[9];
    const float* b_ih_dec  = (const float*)d_in[10];
    const float* b_hh_dec  = (const float*)d_in[11];
    const float* W_dec     = (const float*)d_in[12];
    const float* b_dec     = (const float*)d_in[13];
    const float* W_out     = (const float*)d_in[14];
    const float* b_out     = (const float*)d_in[15];
    float* out = (float*)d_out;
    const int LEN = out_size / (B_ * O_);   // 30
    const int BH = B_ * H_;

    char* ws = (char*)d_ws;
    size_t off = 0;
    auto aus = [&](size_t n) { ushort* p = (ushort*)(ws + off); off += n * 2; return p; };
    auto af  = [&](size_t n) { float*  p = (float*) (ws + off); off += n * 4; return p; };

    // pre-split weights (hot / MFMA-consumed). Decoder LSTM W split on the fly.
    ushort* WhhE_h = aus((size_t)4*H_*H_); ushort* WhhE_l = aus((size_t)4*H_*H_);
    ushort* WihE_h = aus((size_t)4*H_*I_); ushort* WihE_l = aus((size_t)4*H_*I_);
    ushort* Wh_h   = aus((size_t)H_*H_);   ushort* Wh_l   = aus((size_t)H_*H_);
    ushort* Wc_h   = aus((size_t)H_*H_);   ushort* Wc_l   = aus((size_t)H_*H_);
    ushort* Wdec_h = aus((size_t)H_*H_);   ushort* Wdec_l = aus((size_t)H_*H_);
    ushort* Wout_h = aus((size_t)O_*H_);   ushort* Wout_l = aus((size_t)O_*H_);

    ushort* ctx_seq = aus((size_t)T_ * BH);          // encoder h_hi history
    ushort* Hhi0 = aus(BH); ushort* Hhi1 = aus(BH);  // coherent h ring (hi)
    ushort* Hlo0 = aus(BH); ushort* Hlo1 = aus(BH);  // coherent h ring (lo)
    ushort* hd_hi0  = aus(BH); ushort* hd_hi1  = aus(BH);
    ushort* hd_lo0  = aus(BH); ushort* hd_lo1  = aus(BH);
    ushort* ctx_hi  = aus(BH); ushort* ctx_lo  = aus(BH);
    ushort* d1_hi   = aus(BH); ushort* d1_lo   = aus(BH);
    float*  cbuf    = af(BH);
    float*  qbuf    = af(BH);
    float*  scores  = af(B_ * T_);
    unsigned* barbuf = (unsigned*)(ws + off); off += 256;   // grid-barrier state

    // P (fp16, T*B*H = 134.2MB) in two 67.1MB halves.
    const size_t P_HALF = (size_t)(T_ / 2) * BH * 2;   // 67,108,864
    _Float16 *P0, *P1;
    if (ws_size >= off + 2 * P_HALF) {        // layout A: both halves in ws
        P0 = (_Float16*)(ws + off);
        P1 = (_Float16*)(ws + off + P_HALF);
    } else {                                   // layout B: half 1 aliases input_seq
        P0 = (_Float16*)const_cast<float*>(input_seq);   // dead after encoder
        P1 = (_Float16*)(ws + off);            // off ~174MB + 67.1MB <= budget
    }

    // ---- weight split pre-pass ----
    auto spl = [&](const float* src, int srcld, int coloff, ushort* hi, ushort* lo,
                   int R, int K) {
        split_w<<<dim3(K / 256, R), 256, 0, stream>>>(src, srcld, coloff, hi, lo, K);
    };
    spl(W_hh_enc, H_,     0,  WhhE_h, WhhE_l, 4 * H_, H_);
    spl(W_ih_enc, I_,     0,  WihE_h, WihE_l, 4 * H_, I_);
    spl(W_attn,   2 * H_, 0,  Wh_h,   Wh_l,   H_,     H_);
    spl(W_attn,   2 * H_, H_, Wc_h,   Wc_l,   H_,     H_);
    spl(W_dec,    H_,     0,  Wdec_h, Wdec_l, H_,     H_);
    spl(W_out,    H_,     0,  Wout_h, Wout_l, O_,     H_);

    hipMemsetAsync(Hhi1,   0, (size_t)BH * 2, stream);   // h_{-1} = 0 (ring idx 1)
    hipMemsetAsync(Hlo1,   0, (size_t)BH * 2, stream);
    hipMemsetAsync(barbuf, 0, 256, stream);

    // ---- encoder: ONE persistent kernel, 512 steps with internal fence-free
    //      grid barriers. 256 blocks (1/CU -> co-residency guaranteed). ----
    enc_persistent<<<dim3(H_ / 4), 512, ENC_SMEM_BYTES, stream>>>(
        input_seq, WhhE_h, WhhE_l, WihE_h, WihE_l, b_ih_enc, b_hh_enc,
        ctx_seq, Hhi0, Hhi1, Hlo0, Hlo1, barbuf);
    // enc final (t=511, odd -> ring idx 1): hi = ctx_seq[511], lo = Hlo1

    // ---- P = ctx_seq @ W_c^T + b_attn  (fp16, dual region; may overwrite
    //      input_seq — safe: encoder already consumed it) ----
    gemm_mfma<false, 8, 4, false, H_><<<dim3(8, (T_ * B_) / 64), 256, 0, stream>>>(
        ctx_seq, nullptr, H_, Wc_h, Wc_l, b_attn, P0, P1, H_);

    // ---- decoder ----
    hipMemsetAsync(cbuf, 0, (size_t)BH * 4, stream);
    ushort* dhh[2] = {hd_hi0, hd_hi1};
    ushort* dhl[2] = {hd_lo0, hd_lo1};
    for (int s = 0; s < LEN; s++) {
        const ushort* hi_in = (s == 0) ? ctx_seq + (size_t)(T_ - 1) * BH : dhh[s & 1];
        const ushort* lo_in = (s == 0) ? Hlo1 : dhl[s & 1];

        // q = h @ W_h^T (bias folded into P)
        gemm_mfma<true, 1, 0, false, H_><<<dim3(H_ / 16, 2), 256, 0, stream>>>(
            hi_in, lo_in, H_, Wh_h, Wh_l, nullptr, qbuf, nullptr, H_);
        attn_score_kernel<<<T_ * B_ / 4, 256, 0, stream>>>(qbuf, P0, P1, v, scores);
        softmax_kernel<<<B_, 256, 0, stream>>>(scores);
        attn_context_kernel<<<BH / 512, 256, 0, stream>>>(scores, ctx_seq, ctx_hi, ctx_lo);
        // decoder LSTM cell (x = context split; weights split on the fly)
        lstm_mfma<false, true, H_><<<dim3(H_ / 4, 2), 256, 0, stream>>>(
            hi_in, lo_in, (const void*)ctx_hi, ctx_lo,
            W_hh_dec, nullptr, W_ih_dec, nullptr, b_ih_dec, b_hh_dec,
            cbuf, cbuf, dhh[(s + 1) & 1], dhl[(s + 1) & 1]);
        // d1 = relu(h @ W_dec^T + b_dec) -> split
        gemm_mfma<true, 1, 3, true, H_><<<dim3(H_ / 16, 2), 256, 0, stream>>>(
            dhh[(s + 1) & 1], dhl[(s + 1) & 1], H_, Wdec_h, Wdec_l, b_dec,
            d1_hi, d1_lo, H_);
        // out = d1 @ W_out^T + b_out
        gemm_mfma<true, 1, 0, false, H_><<<dim3(O_ / 16, 2), 256, 0, stream>>>(
            d1_hi, d1_lo, H_, Wout_h, Wout_l, b_out,
            out + (size_t)s * B_ * O_, nullptr, O_);
    }
    (void)in_sizes; (void)n_in;
}

// Round 3
// 18621.402 us; speedup vs baseline: 1.6639x; 1.5646x over previous
//
#include <hip/hip_runtime.h>
#include <hip/hip_bf16.h>
#include <type_traits>

// ---------------------------------------------------------------------------
// Seq2SeqAttention R7: panel layout kills partial-line amplification.
//   R6 post-mortem: 5.9 MB/step HBM-side traffic from 8B-per-2KB scattered
//   h stores/loads (write-through RMW on partial 64B lines) -> 39us/step.
//   R7: all h-like [B][H] ushort buffers use PANEL layout:
//        elem(b,h) at ((h>>2)*128 + b)*4 + (h&3)
//   - cell-update stores are thread-linear (1KB contiguous per block).
//   - MFMA A-fragments = two dense 8B loads (128B contiguous per 16 lanes).
//   - encoder hi-state: NO ring; read ctx_seq[t-1] with PLAIN cached loads
//     (virgin address per step -> no stale-line hazard; stores write-through
//     agent atomics -> IC has truth; per-XCD L2 serves 31/32 blocks).
//   - lo residual: 2-slot ring, relaxed agent atomics (dense).
//   - decoder/GEMM A-sides + d1/ctx panelized; attn_context re-threaded;
//     softmax writes transposed weights scT[t][b] for dense context reads.
// MFMA 16x16x32 bf16 layouts (m89/m91-verified): A[m=lane&15][k=quad*8+j],
// B[k=quad*8+j][n=lane&15], D col=lane&15 row=quad*4+reg.
// ---------------------------------------------------------------------------

static constexpr int T_ = 512, B_ = 128, I_ = 256, H_ = 1024, O_ = 256;

typedef unsigned short ushort;
typedef unsigned long long u64;
typedef __attribute__((ext_vector_type(8))) short bf16x8;
typedef __attribute__((ext_vector_type(4))) float f32x4;
typedef __attribute__((ext_vector_type(8))) _Float16 half8;

__device__ __forceinline__ float bf2f(ushort u) {
    union { unsigned i; float f; } cv; cv.i = ((unsigned)u) << 16; return cv.f;
}
__device__ __forceinline__ ushort f2bf(float f) {   // RNE
    union { float f; unsigned u; } c; c.f = f;
    unsigned r = c.u + 0x7FFFu + ((c.u >> 16) & 1u);
    return (ushort)(r >> 16);
}
__device__ __forceinline__ float fast_sigmoid(float x) { return 1.f / (1.f + __expf(-x)); }
__device__ __forceinline__ float fast_tanh(float x) {
    float ax = fabsf(x);
    float e = __expf(-2.f * ax);
    float t = (1.f - e) / (1.f + e);
    return copysignf(t, x);
}
__device__ __forceinline__ f32x4 mfma16(bf16x8 a, bf16x8 b, f32x4 c) {
    return __builtin_amdgcn_mfma_f32_16x16x32_bf16(a, b, c, 0, 0, 0);
}
__device__ __forceinline__ bf16x8 ld8(const ushort* p) { return *(const bf16x8*)(const void*)p; }

// ---- panel-layout fragment loads -------------------------------------------
// h-like buffer [B_=128][H] as [t][chunk=h>>2][b][4]; row = t*128+b.
__device__ __forceinline__ bf16x8 ld8p(const ushort* base, int row, int ko) {
    const size_t t = (size_t)(row >> 7);
    const int b = row & 127;
    const ushort* p0 = base + t * (size_t)(B_ * H_) + ((size_t)((ko >> 2) * B_ + b) << 2);
    union { u64 q[2]; bf16x8 v; } u;
    u.q[0] = *(const u64*)(const void*)p0;
    u.q[1] = *(const u64*)(const void*)(p0 + (B_ << 2));
    return u.v;
}
// coherent (agent, relaxed) variant for the lo ring (IC point-of-coherence)
__device__ __forceinline__ bf16x8 ld8p_cc(const ushort* base, int b, int ko) {
    const ushort* p0 = base + ((size_t)((ko >> 2) * B_ + b) << 2);
    union { u64 q[2]; bf16x8 v; } u;
    u.q[0] = __hip_atomic_load((const u64*)(const void*)p0, __ATOMIC_RELAXED,
                               __HIP_MEMORY_SCOPE_AGENT);
    u.q[1] = __hip_atomic_load((const u64*)(const void*)(p0 + (B_ << 2)),
                               __ATOMIC_RELAXED, __HIP_MEMORY_SCOPE_AGENT);
    return u.v;
}

// ---- split 8 fp32 into bf16 hi/lo fragments --------------------------------
__device__ __forceinline__ void split8(const float* p, bf16x8& hi, bf16x8& lo) {
    #pragma unroll
    for (int j = 0; j < 8; j++) {
        const float f = p[j];
        const ushort h = f2bf(f);
        hi[j] = (short)h;
        lo[j] = (short)f2bf(f - bf2f(h));
    }
}

// ---- weight split pre-pass -------------------------------------------------
__global__ __launch_bounds__(256) void split_w(
    const float* __restrict__ src, int srcld, int coloff,
    ushort* __restrict__ hi, ushort* __restrict__ lo, int K)
{
    const int k = blockIdx.x * 256 + threadIdx.x;
    const int r = blockIdx.y;
    const float f = src[(size_t)r * srcld + coloff + k];
    const ushort h = f2bf(f);
    hi[(size_t)r * K + k] = h;
    lo[(size_t)r * K + k] = f2bf(f - bf2f(h));
}

// ---------------------------------------------------------------------------
// Persistent encoder: 256 blocks (1/CU), 512 threads (8 waves). Block owns
// 4 h-values (16 gate-cols) x all 128 batch rows; wave w = row-tile w*16.
// LDS: Whh hi/lo [32][64][8] + Wih hi/lo [8][64][8] + Gt[16][132].
// hi state: ctx_seq history (plain loads, virgin addresses). lo: 2-ring.
// ---------------------------------------------------------------------------
#define ENC_SMEM_BYTES (32*64*8*2*2 + 8*64*8*2*2 + 16*132*4)   // 90368

__global__ __launch_bounds__(512) void enc_persistent(
    const float* __restrict__ input_seq,
    const ushort* __restrict__ WhhE_h, const ushort* __restrict__ WhhE_l,
    const ushort* __restrict__ WihE_h, const ushort* __restrict__ WihE_l,
    const float* __restrict__ bih, const float* __restrict__ bhh,
    const ushort* __restrict__ hzero,
    ushort* __restrict__ ctx_seq,                  // panel [t][c][b][4], hi history
    ushort* __restrict__ Hlo0, ushort* __restrict__ Hlo1,   // lo ring (panel)
    unsigned* __restrict__ bar)   // bar[0]=cumulative arrivals, bar[1]=released step
{
    extern __shared__ __align__(16) char smem[];
    ushort* LWh = (ushort*)smem;                 // Whh hi  [32][64][8]
    ushort* LWl = LWh + 32 * 64 * 8;             // Whh lo
    ushort* LIh = LWl + 32 * 64 * 8;             // Wih hi  [8][64][8]
    ushort* LIl = LIh + 8 * 64 * 8;              // Wih lo
    float*  Gt  = (float*)(LIl + 8 * 64 * 8);    // [16 cols][132]

    const int tid  = threadIdx.x;
    const int wave = tid >> 6, lane = tid & 63;
    const int quad = lane >> 4, l15 = lane & 15;
    const int bx   = blockIdx.x;
    const int h0   = bx << 2;
    const int wr   = ((l15 >> 2) * H_) + h0 + (l15 & 3);   // gate*H + h row of W

    // ---- stage weights into LDS (lane-major fragments; done once) ----
    {
        const size_t woff = (size_t)wr * H_;
        #pragma unroll
        for (int ii = 0; ii < 4; ii++) {
            const int i   = wave + (ii << 3);          // K-iter index 0..31
            const int src = (i << 5) + (quad << 3);
            *(bf16x8*)(LWh + ((i << 6) + lane) * 8) = ld8(WhhE_h + woff + src);
            *(bf16x8*)(LWl + ((i << 6) + lane) * 8) = ld8(WhhE_l + woff + src);
        }
        const size_t ioff = (size_t)wr * I_;
        const int src2 = (wave << 5) + (quad << 3);    // K-iter index = wave (0..7)
        *(bf16x8*)(LIh + ((wave << 6) + lane) * 8) = ld8(WihE_h + ioff + src2);
        *(bf16x8*)(LIl + ((wave << 6) + lane) * 8) = ld8(WihE_l + ioff + src2);
    }

    // per-thread cell-update mapping + persistent state
    const int bl_  = tid >> 2, hl = tid & 3;
    const int hidx = h0 + hl;
    const float bs0 = bih[hidx]           + bhh[hidx];
    const float bs1 = bih[H_ + hidx]      + bhh[H_ + hidx];
    const float bs2 = bih[2 * H_ + hidx]  + bhh[2 * H_ + hidx];
    const float bs3 = bih[3 * H_ + hidx]  + bhh[3 * H_ + hidx];
    float c_reg = 0.f;
    unsigned genv = 0;
    __syncthreads();

    const int arow = (wave << 4) + l15;   // batch row for MFMA A (0..127)
    const size_t xoff = (size_t)arow * I_;

    for (int t = 0; t < T_; t++) {
        const ushort* hi_src = t ? (ctx_seq + (size_t)(t - 1) * (B_ * H_)) : hzero;
        const ushort* Hp_lo  = (t & 1) ? Hlo0 : Hlo1;
        ushort*       Hc_lo  = (t & 1) ? Hlo1 : Hlo0;
        const float*  xs     = input_seq + (size_t)t * (B_ * I_);

        f32x4 acc0 = {0.f, 0.f, 0.f, 0.f}, acc1 = acc0, acc2 = acc0;
        // segment 1: h @ Whh^T (weights from LDS; hi plain/L2, lo coherent/IC)
        #pragma unroll 8
        for (int kc = 0; kc < H_; kc += 32) {
            const int i  = kc >> 5;
            const int ko = kc + (quad << 3);
            const bf16x8 bh = *(const bf16x8*)(LWh + ((i << 6) + lane) * 8);
            const bf16x8 bl = *(const bf16x8*)(LWl + ((i << 6) + lane) * 8);
            const bf16x8 ah = ld8p(hi_src, arow, ko);
            const bf16x8 al = ld8p_cc(Hp_lo, arow, ko);
            acc0 = mfma16(ah, bh, acc0);
            acc1 = mfma16(ah, bl, acc1);
            acc2 = mfma16(al, bh, acc2);
        }
        // segment 2: x @ Wih^T (x fp32 read-only, split on the fly)
        #pragma unroll
        for (int kc = 0; kc < I_; kc += 32) {
            const int i = kc >> 5;
            const bf16x8 bh = *(const bf16x8*)(LIh + ((i << 6) + lane) * 8);
            const bf16x8 bl = *(const bf16x8*)(LIl + ((i << 6) + lane) * 8);
            bf16x8 ah, al;
            split8(xs + xoff + kc + (quad << 3), ah, al);
            acc0 = mfma16(ah, bh, acc0);
            acc1 = mfma16(ah, bl, acc1);
            acc2 = mfma16(al, bh, acc2);
        }
        // gate exchange: Gt[col][row]; D: row=quad*4+r, col=l15
        #pragma unroll
        for (int r = 0; r < 4; r++)
            Gt[l15 * 132 + (wave << 4) + (quad << 2) + r] = acc0[r] + acc1[r] + acc2[r];
        __syncthreads();

        // cell update (thread -> (batch row bl_, h-local hl)); c in register
        const float gi = Gt[hl * 132 + bl_]        + bs0;
        const float gf = Gt[(4 + hl) * 132 + bl_]  + bs1;
        const float gg = Gt[(8 + hl) * 132 + bl_]  + bs2;
        const float go = Gt[(12 + hl) * 132 + bl_] + bs3;
        const float ig = fast_sigmoid(gi), fg = fast_sigmoid(gf);
        const float gtv = fast_tanh(gg),   og = fast_sigmoid(go);
        c_reg = fg * c_reg + ig * gtv;
        const float hnew = og * fast_tanh(c_reg);
        const ushort hh  = f2bf(hnew);
        const ushort hlo = f2bf(hnew - bf2f(hh));

        // panel stores: thread-linear -> fully coalesced packed 4B atomics
        const unsigned hp = (unsigned)hh  | (__shfl_down((unsigned)hh, 1)  << 16);
        const unsigned lp = (unsigned)hlo | (__shfl_down((unsigned)hlo, 1) << 16);
        if (!(tid & 1)) {
            const size_t ci = (size_t)t * (B_ * H_) + ((size_t)bx << 9) + (unsigned)tid;
            __hip_atomic_store((unsigned*)(void*)&ctx_seq[ci], hp,
                               __ATOMIC_RELAXED, __HIP_MEMORY_SCOPE_AGENT);
            __hip_atomic_store((unsigned*)(void*)&Hc_lo[((unsigned)bx << 9) + tid], lp,
                               __ATOMIC_RELAXED, __HIP_MEMORY_SCOPE_AGENT);
        }

        // fence-free grid barrier (monotonic arrivals)
        if (t != T_ - 1) {
            __syncthreads();   // drains vmcnt: stores retired (IC-visible) pre-arrival
            if (tid == 0) {
                const unsigned arrived =
                    __hip_atomic_fetch_add(&bar[0], 1u, __ATOMIC_RELAXED,
                                           __HIP_MEMORY_SCOPE_AGENT) + 1;
                const unsigned target = ++genv;
                if (arrived == target * 256u) {
                    __hip_atomic_store(&bar[1], target, __ATOMIC_RELAXED,
                                       __HIP_MEMORY_SCOPE_AGENT);
                } else {
                    while (__hip_atomic_load(&bar[1], __ATOMIC_RELAXED,
                                             __HIP_MEMORY_SCOPE_AGENT) < target)
                        __builtin_amdgcn_s_sleep(2);
                }
            }
            __syncthreads();
        }
    }
}

// ---- fused LSTM step (decoder). Block: 64 batch rows x 16 gate-cols. -------
// grid (H/4 = 256 colgroups, 2 row-halves). A-side h/x PANEL layout.
template<bool WSPLIT, bool XSPLIT, int KX>
__global__ __launch_bounds__(256) void lstm_mfma(
    const ushort* __restrict__ h_hi, const ushort* __restrict__ h_lo,
    const void* __restrict__ x_p, const ushort* __restrict__ x_lo,
    const void* __restrict__ Whh_a, const void* __restrict__ Whh_b,
    const void* __restrict__ Wih_a, const void* __restrict__ Wih_b,
    const float* __restrict__ bih, const float* __restrict__ bhh,
    const float* __restrict__ c_in, float* __restrict__ c_out,
    ushort* __restrict__ h_out_hi, ushort* __restrict__ h_out_lo)
{
    __shared__ float Gt[16][65];
    const int tid = threadIdx.x;
    const int wave = tid >> 6, lane = tid & 63;
    const int quad = lane >> 4, l15 = lane & 15;
    const int h0 = blockIdx.x << 2;
    const int mbase = (blockIdx.y << 6) + (wave << 4);
    const int arow = mbase + l15;
    const int wr = ((l15 >> 2) * H_) + h0 + (l15 & 3);   // gate*H + h index

    f32x4 acc0 = {0.f,0.f,0.f,0.f}, acc1 = acc0, acc2 = acc0;

    // segment 1: h @ Whh^T, K = 1024, A split (hi+lo), panel A
    {
        const size_t woff = (size_t)wr * H_;
        #pragma unroll 4
        for (int kc = 0; kc < H_; kc += 32) {
            const int ko = kc + quad * 8;
            bf16x8 bh, bl;
            if constexpr (WSPLIT) {
                bh = ld8((const ushort*)Whh_a + woff + ko);
                bl = ld8((const ushort*)Whh_b + woff + ko);
            } else {
                split8((const float*)Whh_a + woff + ko, bh, bl);
            }
            const bf16x8 ah = ld8p(h_hi, arow, ko);
            const bf16x8 al = ld8p(h_lo, arow, ko);
            acc0 = mfma16(ah, bh, acc0);
            acc1 = mfma16(ah, bl, acc1);
            acc2 = mfma16(al, bh, acc2);
        }
    }
    // segment 2: x @ Wih^T, K = KX (x panel when XSPLIT)
    {
        const size_t woff = (size_t)wr * KX;
        #pragma unroll 2
        for (int kc = 0; kc < KX; kc += 32) {
            const int ko = kc + quad * 8;
            bf16x8 bh, bl;
            if constexpr (WSPLIT) {
                bh = ld8((const ushort*)Wih_a + woff + ko);
                bl = ld8((const ushort*)Wih_b + woff + ko);
            } else {
                split8((const float*)Wih_a + woff + ko, bh, bl);
            }
            bf16x8 ah, al;
            if constexpr (XSPLIT) {
                ah = ld8p((const ushort*)x_p, arow, ko);
                al = ld8p(x_lo, arow, ko);
            } else {
                split8((const float*)x_p + (size_t)arow * KX + ko, ah, al);
            }
            acc0 = mfma16(ah, bh, acc0);
            acc1 = mfma16(ah, bl, acc1);
            acc2 = mfma16(al, bh, acc2);
        }
    }
    // gate exchange: Gt[col][local_row]; D: row=quad*4+r, col=l15
    #pragma unroll
    for (int r = 0; r < 4; r++)
        Gt[l15][(wave << 4) + quad * 4 + r] = acc0[r] + acc1[r] + acc2[r];
    __syncthreads();

    // cell update: thread -> (local batch row, h-local)
    const int bl_ = tid >> 2, hl = tid & 3;
    const int b = (blockIdx.y << 6) + bl_;
    const int hidx = h0 + hl;
    const float gi = Gt[hl][bl_]      + bih[hidx]          + bhh[hidx];
    const float gf = Gt[4 + hl][bl_]  + bih[H_ + hidx]     + bhh[H_ + hidx];
    const float gg = Gt[8 + hl][bl_]  + bih[2 * H_ + hidx] + bhh[2 * H_ + hidx];
    const float go = Gt[12 + hl][bl_] + bih[3 * H_ + hidx] + bhh[3 * H_ + hidx];
    const float ig = fast_sigmoid(gi), fg = fast_sigmoid(gf);
    const float gt = fast_tanh(gg),    og = fast_sigmoid(go);
    const float cold = c_in[b * H_ + hidx];
    const float cnew = fg * cold + ig * gt;
    const float hnew = og * fast_tanh(cnew);
    c_out[b * H_ + hidx] = cnew;
    const ushort hh = f2bf(hnew);
    const size_t op = ((size_t)(hidx >> 2) * B_ + b) * 4 + (hidx & 3);   // panel
    h_out_hi[op] = hh;
    h_out_lo[op] = f2bf(hnew - bf2f(hh));
}

// ---- generic MFMA GEMM: C = act(A @ W^T + bias) ----------------------------
// grid (N/(16*NT), M/64). Wave = 1 M-tile(16 rows) x NT N-tiles.
// APANEL: A in panel layout. OM: 0=f32 row-major, 3=split bf16 PANEL out,
// 4=fp16 dual-region row-major (idx<HALF -> out0)
template<bool A_LO, int NT, int OM, bool RELU, int K, bool APANEL>
__global__ __launch_bounds__(256) void gemm_mfma(
    const ushort* __restrict__ Ahi, const ushort* __restrict__ Alo, int lda,
    const ushort* __restrict__ Whi, const ushort* __restrict__ Wlo,
    const float* __restrict__ bias,
    void* __restrict__ out0, void* __restrict__ out1, int ldc)
{
    const int tid = threadIdx.x;
    const int wave = tid >> 6, lane = tid & 63;
    const int quad = lane >> 4, l15 = lane & 15;
    const int colbase = (blockIdx.x * NT) << 4;
    const int row = (blockIdx.y << 6) + (wave << 4) + l15;
    const size_t aoff = (size_t)row * lda;

    f32x4 acc0[NT], acc1[NT], acc2[NT];
    #pragma unroll
    for (int nt = 0; nt < NT; nt++) {
        acc0[nt] = {0.f,0.f,0.f,0.f}; acc1[nt] = acc0[nt]; acc2[nt] = acc0[nt];
    }
    size_t woff[NT];
    #pragma unroll
    for (int nt = 0; nt < NT; nt++)
        woff[nt] = (size_t)(colbase + (nt << 4) + l15) * K;

    #pragma unroll 2
    for (int kc = 0; kc < K; kc += 32) {
        const int ko = kc + quad * 8;
        const bf16x8 ah = APANEL ? ld8p(Ahi, row, ko) : ld8(Ahi + aoff + ko);
        bf16x8 al;
        if (A_LO) al = APANEL ? ld8p(Alo, row, ko) : ld8(Alo + aoff + ko);
        #pragma unroll
        for (int nt = 0; nt < NT; nt++) {
            const bf16x8 bh = ld8(Whi + woff[nt] + ko);
            const bf16x8 bl = ld8(Wlo + woff[nt] + ko);
            acc0[nt] = mfma16(ah, bh, acc0[nt]);
            acc1[nt] = mfma16(ah, bl, acc1[nt]);
            if (A_LO) acc2[nt] = mfma16(al, bh, acc2[nt]);
        }
    }
    const size_t orow0 = ((size_t)blockIdx.y << 6) + (wave << 4) + quad * 4;
    const size_t HALF_IDX = (size_t)32768 * 1024;   // P region boundary
    #pragma unroll
    for (int nt = 0; nt < NT; nt++) {
        const int col = colbase + (nt << 4) + l15;
        const float bv = bias ? bias[col] : 0.f;
        #pragma unroll
        for (int r = 0; r < 4; r++) {
            float v = acc0[nt][r] + acc1[nt][r] + (A_LO ? acc2[nt][r] : 0.f) + bv;
            if (RELU) v = fmaxf(v, 0.f);
            const size_t idx = (orow0 + r) * (size_t)ldc + col;
            if constexpr (OM == 0) {
                ((float*)out0)[idx] = v;
            } else if constexpr (OM == 3) {     // panel bf16 hi/lo
                const size_t idxp = ((size_t)(col >> 2) * B_ + (orow0 + r)) * 4 + (col & 3);
                const ushort h = f2bf(v);
                ((ushort*)out0)[idxp] = h;
                ((ushort*)out1)[idxp] = f2bf(v - bf2f(h));
            } else {   // OM == 4: fp16 dual region, row-major
                if (idx < HALF_IDX) ((_Float16*)out0)[idx] = (_Float16)v;
                else                ((_Float16*)out1)[idx - HALF_IDX] = (_Float16)v;
            }
        }
    }
}

// ---- scores[b][t] = sum_h v[h]*tanh(q[b][h] + P[t][b][h]); P fp16 2-region -
__global__ __launch_bounds__(256) void attn_score_kernel(
    const float* __restrict__ q,
    const _Float16* __restrict__ P0, const _Float16* __restrict__ P1,
    const float* __restrict__ v, float* __restrict__ scores)
{
    const int wave = threadIdx.x >> 6, lane = threadIdx.x & 63;
    const int p = (blockIdx.x << 2) + wave;
    const int t = p >> 7, b = p & 127;
    const size_t base = (size_t)(t * B_ + b) * H_ + (lane << 4);
    const size_t HALF_IDX = (size_t)32768 * 1024;
    const _Float16* pp = (base < HALF_IDX) ? (P0 + base) : (P1 + (base - HALF_IDX));

    const half8 u0 = *(const half8*)(const void*)pp;
    const half8 u1 = *(const half8*)(const void*)(pp + 8);
    float pv[16];
    #pragma unroll
    for (int j = 0; j < 8; j++) { pv[j] = (float)u0[j]; pv[8 + j] = (float)u1[j]; }

    const float* qp = q + b * H_ + (lane << 4);
    const float* vp = v + (lane << 4);
    float sum = 0.f;
    #pragma unroll
    for (int j0 = 0; j0 < 16; j0 += 4) {
        const float4 qv = *(const float4*)(qp + j0);
        const float4 vv = *(const float4*)(vp + j0);
        sum += vv.x * fast_tanh(qv.x + pv[j0 + 0]);
        sum += vv.y * fast_tanh(qv.y + pv[j0 + 1]);
        sum += vv.z * fast_tanh(qv.z + pv[j0 + 2]);
        sum += vv.w * fast_tanh(qv.w + pv[j0 + 3]);
    }
    #pragma unroll
    for (int off = 32; off; off >>= 1) sum += __shfl_down(sum, off);
    if (lane == 0) scores[b * T_ + t] = sum;
}

// ---- softmax over t; reads scores[b][t], writes transposed scT[t][b] -------
__global__ __launch_bounds__(256) void softmax_kernel(
    const float* __restrict__ scores, float* __restrict__ scT)
{
    __shared__ float red[256];
    const int b = blockIdx.x, tid = threadIdx.x;
    const float s0 = scores[b * T_ + tid];
    const float s1 = scores[b * T_ + tid + 256];
    red[tid] = fmaxf(s0, s1);
    __syncthreads();
    for (int off = 128; off; off >>= 1) {
        if (tid < off) red[tid] = fmaxf(red[tid], red[tid + off]);
        __syncthreads();
    }
    const float mx = red[0];
    __syncthreads();
    const float e0 = __expf(s0 - mx), e1 = __expf(s1 - mx);
    red[tid] = e0 + e1;
    __syncthreads();
    for (int off = 128; off; off >>= 1) {
        if (tid < off) red[tid] += red[tid + off];
        __syncthreads();
    }
    const float inv = 1.f / red[0];
    scT[tid * B_ + b] = e0 * inv;
    scT[(tid + 256) * B_ + b] = e1 * inv;
}

// ---- context (panel): ctx_hi/lo[c][b][4] = sum_t scT[t][b]*ctx[t][c][b][4] -
__global__ __launch_bounds__(256) void attn_context_kernel(
    const float* __restrict__ scT, const ushort* __restrict__ ctx,
    ushort* __restrict__ chi, ushort* __restrict__ clo)
{
    const int u = blockIdx.x * 256 + threadIdx.x;   // 32768 threads
    const int c = u >> 7, b = u & 127;
    const ushort* cp = ctx + ((size_t)(c * B_ + b) << 2);
    const float* wp = scT + b;
    float a0 = 0.f, a1 = 0.f, a2 = 0.f, a3 = 0.f;
    #pragma unroll 4
    for (int t = 0; t < T_; t++) {
        const float w = wp[t << 7];
        const u64 raw = *(const u64*)(const void*)(cp + (size_t)t * (B_ * H_));
        a0 += w * bf2f((ushort)raw);
        a1 += w * bf2f((ushort)(raw >> 16));
        a2 += w * bf2f((ushort)(raw >> 32));
        a3 += w * bf2f((ushort)(raw >> 48));
    }
    const size_t i0 = (size_t)(c * B_ + b) << 2;
    const ushort h0 = f2bf(a0), h1 = f2bf(a1), h2 = f2bf(a2), h3 = f2bf(a3);
    const ushort l0 = f2bf(a0 - bf2f(h0)), l1 = f2bf(a1 - bf2f(h1));
    const ushort l2 = f2bf(a2 - bf2f(h2)), l3 = f2bf(a3 - bf2f(h3));
    *(u64*)(void*)&chi[i0] = (u64)h0 | ((u64)h1 << 16) | ((u64)h2 << 32) | ((u64)h3 << 48);
    *(u64*)(void*)&clo[i0] = (u64)l0 | ((u64)l1 << 16) | ((u64)l2 << 32) | ((u64)l3 << 48);
}

// ---------------------------------------------------------------------------
extern "C" void kernel_launch(void* const* d_in, const int* in_sizes, int n_in,
                              void* d_out, int out_size, void* d_ws, size_t ws_size,
                              hipStream_t stream)
{
    const float* input_seq = (const float*)d_in[0];
    const float* W_ih_enc  = (const float*)d_in[1];
    const float* W_hh_enc  = (const float*)d_in[2];
    const float* b_ih_enc  = (const float*)d_in[3];
    const float* b_hh_enc  = (const float*)d_in[4];
    const float* W_attn    = (const float*)d_in[5];
    const float* b_attn    = (const float*)d_in[6];
    const float* v         = (const float*)d_in[7];
    const float* W_ih_dec  = (const float*)d_in[8];
    const float* W_hh_dec  = (const float*)d_in[9];
    const float* b_ih_dec  = (const float*)d_in[10];
    const float* b_hh_dec  = (const float*)d_in[11];
    const float* W_dec     = (const float*)d_in[12];
    const float* b_dec     = (const float*)d_in[13];
    const float* W_out     = (const float*)d_in[14];
    const float* b_out     = (const float*)d_in[15];
    float* out = (float*)d_out;
    const int LEN = out_size / (B_ * O_);   // 30
    const int BH = B_ * H_;

    char* ws = (char*)d_ws;
    size_t off = 0;
    auto aus = [&](size_t n) { ushort* p = (ushort*)(ws + off); off += n * 2; return p; };
    auto af  = [&](size_t n) { float*  p = (float*) (ws + off); off += n * 4; return p; };

    // pre-split weights (hot / MFMA-consumed). Decoder LSTM W split on the fly.
    ushort* WhhE_h = aus((size_t)4*H_*H_); ushort* WhhE_l = aus((size_t)4*H_*H_);
    ushort* WihE_h = aus((size_t)4*H_*I_); ushort* WihE_l = aus((size_t)4*H_*I_);
    ushort* Wh_h   = aus((size_t)H_*H_);   ushort* Wh_l   = aus((size_t)H_*H_);
    ushort* Wc_h   = aus((size_t)H_*H_);   ushort* Wc_l   = aus((size_t)H_*H_);
    ushort* Wdec_h = aus((size_t)H_*H_);   ushort* Wdec_l = aus((size_t)H_*H_);
    ushort* Wout_h = aus((size_t)O_*H_);   ushort* Wout_l = aus((size_t)O_*H_);

    ushort* ctx_seq = aus((size_t)T_ * BH);          // hi history, panel layout
    ushort* hzero   = aus(BH);
    ushort* Hlo0 = aus(BH); ushort* Hlo1 = aus(BH);  // lo ring (panel)
    ushort* hd_hi0  = aus(BH); ushort* hd_hi1  = aus(BH);
    ushort* hd_lo0  = aus(BH); ushort* hd_lo1  = aus(BH);
    ushort* ctx_hi  = aus(BH); ushort* ctx_lo  = aus(BH);
    ushort* d1_hi   = aus(BH); ushort* d1_lo   = aus(BH);
    float*  cbuf    = af(BH);
    float*  qbuf    = af(BH);
    float*  scores  = af(B_ * T_);
    float*  scT     = af(B_ * T_);
    unsigned* barbuf = (unsigned*)(ws + off); off += 256;   // grid-barrier state

    // P (fp16, T*B*H = 134.2MB) in two 67.1MB halves.
    const size_t P_HALF = (size_t)(T_ / 2) * BH * 2;   // 67,108,864
    _Float16 *P0, *P1;
    if (ws_size >= off + 2 * P_HALF) {        // layout A: both halves in ws
        P0 = (_Float16*)(ws + off);
        P1 = (_Float16*)(ws + off + P_HALF);
    } else {                                   // layout B: half 1 aliases input_seq
        P0 = (_Float16*)const_cast<float*>(input_seq);   // dead after encoder
        P1 = (_Float16*)(ws + off);            // off ~172MB + 67.1MB <= budget
    }

    // ---- weight split pre-pass ----
    auto spl = [&](const float* src, int srcld, int coloff, ushort* hi, ushort* lo,
                   int R, int K) {
        split_w<<<dim3(K / 256, R), 256, 0, stream>>>(src, srcld, coloff, hi, lo, K);
    };
    spl(W_hh_enc, H_,     0,  WhhE_h, WhhE_l, 4 * H_, H_);
    spl(W_ih_enc, I_,     0,  WihE_h, WihE_l, 4 * H_, I_);
    spl(W_attn,   2 * H_, 0,  Wh_h,   Wh_l,   H_,     H_);
    spl(W_attn,   2 * H_, H_, Wc_h,   Wc_l,   H_,     H_);
    spl(W_dec,    H_,     0,  Wdec_h, Wdec_l, H_,     H_);
    spl(W_out,    H_,     0,  Wout_h, Wout_l, O_,     H_);

    hipMemsetAsync(hzero,  0, (size_t)BH * 2, stream);   // h_{-1} = 0
    hipMemsetAsync(Hlo1,   0, (size_t)BH * 2, stream);   // lo_{-1} = 0 (t=0 reads Hlo1)
    hipMemsetAsync(barbuf, 0, 256, stream);

    // ---- encoder: ONE persistent kernel, 512 steps, fence-free barriers ----
    enc_persistent<<<dim3(H_ / 4), 512, ENC_SMEM_BYTES, stream>>>(
        input_seq, WhhE_h, WhhE_l, WihE_h, WihE_l, b_ih_enc, b_hh_enc,
        hzero, ctx_seq, Hlo0, Hlo1, barbuf);
    // enc final (t=511, odd -> lo in Hlo1): hi = ctx_seq[511] (panel)

    // ---- P = ctx_seq @ W_c^T + b_attn  (fp16 row-major, dual region; may
    //      overwrite input_seq — safe: encoder already consumed it) ----
    gemm_mfma<false, 8, 4, false, H_, true><<<dim3(8, (T_ * B_) / 64), 256, 0, stream>>>(
        ctx_seq, nullptr, H_, Wc_h, Wc_l, b_attn, P0, P1, H_);

    // ---- decoder ----
    hipMemsetAsync(cbuf, 0, (size_t)BH * 4, stream);
    ushort* dhh[2] = {hd_hi0, hd_hi1};
    ushort* dhl[2] = {hd_lo0, hd_lo1};
    for (int s = 0; s < LEN; s++) {
        const ushort* hi_in = (s == 0) ? ctx_seq + (size_t)(T_ - 1) * BH : dhh[s & 1];
        const ushort* lo_in = (s == 0) ? Hlo1 : dhl[s & 1];

        // q = h @ W_h^T (bias folded into P)
        gemm_mfma<true, 1, 0, false, H_, true><<<dim3(H_ / 16, 2), 256, 0, stream>>>(
            hi_in, lo_in, H_, Wh_h, Wh_l, nullptr, qbuf, nullptr, H_);
        attn_score_kernel<<<T_ * B_ / 4, 256, 0, stream>>>(qbuf, P0, P1, v, scores);
        softmax_kernel<<<B_, 256, 0, stream>>>(scores, scT);
        attn_context_kernel<<<BH / 4 / 256, 256, 0, stream>>>(scT, ctx_seq, ctx_hi, ctx_lo);
        // decoder LSTM cell (x = context panel; weights split on the fly)
        lstm_mfma<false, true, H_><<<dim3(H_ / 4, 2), 256, 0, stream>>>(
            hi_in, lo_in, (const void*)ctx_hi, ctx_lo,
            W_hh_dec, nullptr, W_ih_dec, nullptr, b_ih_dec, b_hh_dec,
            cbuf, cbuf, dhh[(s + 1) & 1], dhl[(s + 1) & 1]);
        // d1 = relu(h @ W_dec^T + b_dec) -> split (panel out)
        gemm_mfma<true, 1, 3, true, H_, true><<<dim3(H_ / 16, 2), 256, 0, stream>>>(
            dhh[(s + 1) & 1], dhl[(s + 1) & 1], H_, Wdec_h, Wdec_l, b_dec,
            d1_hi, d1_lo, H_);
        // out = d1 @ W_out^T + b_out  (fp32 row-major final output)
        gemm_mfma<true, 1, 0, false, H_, true><<<dim3(O_ / 16, 2), 256, 0, stream>>>(
            d1_hi, d1_lo, H_, Wout_h, Wout_l, b_out,
            out + (size_t)s * B_ * O_, nullptr, O_);
    }
    (void)in_sizes; (void)n_in;
}

// Round 4
// 16640.425 us; speedup vs baseline: 1.8620x; 1.1190x over previous
//
#include <hip/hip_runtime.h>
#include <hip/hip_bf16.h>
#include <type_traits>

// ---------------------------------------------------------------------------
// Seq2SeqAttention R8: virgin-address lo ring (kills sc1/IC re-reads).
//   R7 post-mortem: lo ring read with agent-scope atomic loads = L2 BYPASS
//   (agent PoC is the IC) -> 32 blocks/XCD re-pull 256KB lo from IC each
//   step = 64 MB/step grid-wide at ~3.3 TB/s = the whole 19.1us/step.
//   R8: lo ring becomes 256 slots (67.1 MB, aliases the P1 region which is
//   written only after the encoder). Stores stay sc1 write-through (IC has
//   truth); reads become PLAIN loads at a 256-step-virgin address (L2/L1
//   churn ~3x capacity per step guarantees eviction) -> L2-dedup'd like hi.
//   Also: x @ Wih segment moved BEFORE the barrier wait (h-independent) to
//   hide release latency; arrive/wait split accordingly.
// MFMA 16x16x32 bf16 layouts (m89/m91-verified): A[m=lane&15][k=quad*8+j],
// B[k=quad*8+j][n=lane&15], D col=lane&15 row=quad*4+reg.
// ---------------------------------------------------------------------------

static constexpr int T_ = 512, B_ = 128, I_ = 256, H_ = 1024, O_ = 256;

typedef unsigned short ushort;
typedef unsigned long long u64;
typedef __attribute__((ext_vector_type(8))) short bf16x8;
typedef __attribute__((ext_vector_type(4))) float f32x4;
typedef __attribute__((ext_vector_type(8))) _Float16 half8;

__device__ __forceinline__ float bf2f(ushort u) {
    union { unsigned i; float f; } cv; cv.i = ((unsigned)u) << 16; return cv.f;
}
__device__ __forceinline__ ushort f2bf(float f) {   // RNE
    union { float f; unsigned u; } c; c.f = f;
    unsigned r = c.u + 0x7FFFu + ((c.u >> 16) & 1u);
    return (ushort)(r >> 16);
}
__device__ __forceinline__ float fast_sigmoid(float x) { return 1.f / (1.f + __expf(-x)); }
__device__ __forceinline__ float fast_tanh(float x) {
    float ax = fabsf(x);
    float e = __expf(-2.f * ax);
    float t = (1.f - e) / (1.f + e);
    return copysignf(t, x);
}
__device__ __forceinline__ f32x4 mfma16(bf16x8 a, bf16x8 b, f32x4 c) {
    return __builtin_amdgcn_mfma_f32_16x16x32_bf16(a, b, c, 0, 0, 0);
}
__device__ __forceinline__ bf16x8 ld8(const ushort* p) { return *(const bf16x8*)(const void*)p; }

// ---- panel-layout fragment loads -------------------------------------------
// h-like buffer [B_=128][H] as [t][chunk=h>>2][b][4]; row = t*128+b.
__device__ __forceinline__ bf16x8 ld8p(const ushort* base, int row, int ko) {
    const size_t t = (size_t)(row >> 7);
    const int b = row & 127;
    const ushort* p0 = base + t * (size_t)(B_ * H_) + ((size_t)((ko >> 2) * B_ + b) << 2);
    union { u64 q[2]; bf16x8 v; } u;
    u.q[0] = *(const u64*)(const void*)p0;
    u.q[1] = *(const u64*)(const void*)(p0 + (B_ << 2));
    return u.v;
}

// ---- split 8 fp32 into bf16 hi/lo fragments --------------------------------
__device__ __forceinline__ void split8(const float* p, bf16x8& hi, bf16x8& lo) {
    #pragma unroll
    for (int j = 0; j < 8; j++) {
        const float f = p[j];
        const ushort h = f2bf(f);
        hi[j] = (short)h;
        lo[j] = (short)f2bf(f - bf2f(h));
    }
}

// ---- weight split pre-pass -------------------------------------------------
__global__ __launch_bounds__(256) void split_w(
    const float* __restrict__ src, int srcld, int coloff,
    ushort* __restrict__ hi, ushort* __restrict__ lo, int K)
{
    const int k = blockIdx.x * 256 + threadIdx.x;
    const int r = blockIdx.y;
    const float f = src[(size_t)r * srcld + coloff + k];
    const ushort h = f2bf(f);
    hi[(size_t)r * K + k] = h;
    lo[(size_t)r * K + k] = f2bf(f - bf2f(h));
}

// ---------------------------------------------------------------------------
// Persistent encoder: 256 blocks (1/CU), 512 threads (8 waves). Block owns
// 4 h-values (16 gate-cols) x all 128 batch rows; wave w = row-tile w*16.
// LDS: Whh hi/lo [32][64][8] + Wih hi/lo [8][64][8] + Gt[16][132].
// hi: ctx_seq history (plain loads, virgin). lo: 256-slot virgin ring.
// ---------------------------------------------------------------------------
#define ENC_SMEM_BYTES (32*64*8*2*2 + 8*64*8*2*2 + 16*132*4)   // 90368
#define LORING_SLOTS 256

__global__ __launch_bounds__(512) void enc_persistent(
    const float* __restrict__ input_seq,
    const ushort* __restrict__ WhhE_h, const ushort* __restrict__ WhhE_l,
    const ushort* __restrict__ WihE_h, const ushort* __restrict__ WihE_l,
    const float* __restrict__ bih, const float* __restrict__ bhh,
    const ushort* __restrict__ hzero,
    ushort* __restrict__ ctx_seq,                 // panel [t][c][b][4], hi history
    ushort* __restrict__ loring,                  // panel ring [256][c][b][4]
    ushort* __restrict__ enc_lo_fin,              // final lo (survives P-GEMM)
    unsigned* __restrict__ bar)   // bar[0]=cumulative arrivals, bar[1]=released step
{
    extern __shared__ __align__(16) char smem[];
    ushort* LWh = (ushort*)smem;                 // Whh hi  [32][64][8]
    ushort* LWl = LWh + 32 * 64 * 8;             // Whh lo
    ushort* LIh = LWl + 32 * 64 * 8;             // Wih hi  [8][64][8]
    ushort* LIl = LIh + 8 * 64 * 8;              // Wih lo
    float*  Gt  = (float*)(LIl + 8 * 64 * 8);    // [16 cols][132]

    const int tid  = threadIdx.x;
    const int wave = tid >> 6, lane = tid & 63;
    const int quad = lane >> 4, l15 = lane & 15;
    const int bx   = blockIdx.x;
    const int h0   = bx << 2;
    const int wr   = ((l15 >> 2) * H_) + h0 + (l15 & 3);   // gate*H + h row of W

    // ---- stage weights into LDS (lane-major fragments; done once) ----
    {
        const size_t woff = (size_t)wr * H_;
        #pragma unroll
        for (int ii = 0; ii < 4; ii++) {
            const int i   = wave + (ii << 3);          // K-iter index 0..31
            const int src = (i << 5) + (quad << 3);
            *(bf16x8*)(LWh + ((i << 6) + lane) * 8) = ld8(WhhE_h + woff + src);
            *(bf16x8*)(LWl + ((i << 6) + lane) * 8) = ld8(WhhE_l + woff + src);
        }
        const size_t ioff = (size_t)wr * I_;
        const int src2 = (wave << 5) + (quad << 3);    // K-iter index = wave (0..7)
        *(bf16x8*)(LIh + ((wave << 6) + lane) * 8) = ld8(WihE_h + ioff + src2);
        *(bf16x8*)(LIl + ((wave << 6) + lane) * 8) = ld8(WihE_l + ioff + src2);
    }

    // per-thread cell-update mapping + persistent state
    const int bl_  = tid >> 2, hl = tid & 3;
    const int hidx = h0 + hl;
    const float bs0 = bih[hidx]           + bhh[hidx];
    const float bs1 = bih[H_ + hidx]      + bhh[H_ + hidx];
    const float bs2 = bih[2 * H_ + hidx]  + bhh[2 * H_ + hidx];
    const float bs3 = bih[3 * H_ + hidx]  + bhh[3 * H_ + hidx];
    float c_reg = 0.f;
    __syncthreads();

    const int arow = (wave << 4) + l15;   // batch row for MFMA A (0..127)
    const size_t xoff = (size_t)arow * I_;

    for (int t = 0; t < T_; t++) {
        const float* xs = input_seq + (size_t)t * (B_ * I_);

        f32x4 acc0 = {0.f, 0.f, 0.f, 0.f}, acc1 = acc0, acc2 = acc0;
        // ---- segment 2 FIRST: x @ Wih^T (h-independent; overlaps barrier) --
        #pragma unroll
        for (int kc = 0; kc < I_; kc += 32) {
            const int i = kc >> 5;
            const bf16x8 bh = *(const bf16x8*)(LIh + ((i << 6) + lane) * 8);
            const bf16x8 bl = *(const bf16x8*)(LIl + ((i << 6) + lane) * 8);
            bf16x8 ah, al;
            split8(xs + xoff + kc + (quad << 3), ah, al);
            acc0 = mfma16(ah, bh, acc0);
            acc1 = mfma16(ah, bl, acc1);
            acc2 = mfma16(al, bh, acc2);
        }

        // ---- wait: h_{t-1} published (release of step t) ----
        if (t != 0) {
            if (tid == 0) {
                while (__hip_atomic_load(&bar[1], __ATOMIC_RELAXED,
                                         __HIP_MEMORY_SCOPE_AGENT) < (unsigned)t)
                    __builtin_amdgcn_s_sleep(2);
            }
            __syncthreads();
        }

        // ---- segment 1: h @ Whh^T (weights LDS; hi+lo plain virgin loads) --
        const ushort* hi_src = t ? (ctx_seq + (size_t)(t - 1) * (B_ * H_)) : hzero;
        const ushort* lo_src = t ? (loring + (size_t)((t - 1) & (LORING_SLOTS - 1))
                                             * (B_ * H_)) : hzero;
        #pragma unroll 8
        for (int kc = 0; kc < H_; kc += 32) {
            const int i  = kc >> 5;
            const int ko = kc + (quad << 3);
            const bf16x8 bh = *(const bf16x8*)(LWh + ((i << 6) + lane) * 8);
            const bf16x8 bl = *(const bf16x8*)(LWl + ((i << 6) + lane) * 8);
            const bf16x8 ah = ld8p(hi_src, arow, ko);
            const bf16x8 al = ld8p(lo_src, arow, ko);
            acc0 = mfma16(ah, bh, acc0);
            acc1 = mfma16(ah, bl, acc1);
            acc2 = mfma16(al, bh, acc2);
        }
        // gate exchange: Gt[col][row]; D: row=quad*4+r, col=l15
        #pragma unroll
        for (int r = 0; r < 4; r++)
            Gt[l15 * 132 + (wave << 4) + (quad << 2) + r] = acc0[r] + acc1[r] + acc2[r];
        __syncthreads();

        // cell update (thread -> (batch row bl_, h-local hl)); c in register
        const float gi = Gt[hl * 132 + bl_]        + bs0;
        const float gf = Gt[(4 + hl) * 132 + bl_]  + bs1;
        const float gg = Gt[(8 + hl) * 132 + bl_]  + bs2;
        const float go = Gt[(12 + hl) * 132 + bl_] + bs3;
        const float ig = fast_sigmoid(gi), fg = fast_sigmoid(gf);
        const float gtv = fast_tanh(gg),   og = fast_sigmoid(go);
        c_reg = fg * c_reg + ig * gtv;
        const float hnew = og * fast_tanh(c_reg);
        const ushort hh  = f2bf(hnew);
        const ushort hlo = f2bf(hnew - bf2f(hh));

        // panel stores: thread-linear packed 4B sc1 write-through (IC truth)
        const unsigned hp = (unsigned)hh  | (__shfl_down((unsigned)hh, 1)  << 16);
        const unsigned lp = (unsigned)hlo | (__shfl_down((unsigned)hlo, 1) << 16);
        const unsigned pi = ((unsigned)bx << 9) + (unsigned)tid;
        if (!(tid & 1)) {
            __hip_atomic_store((unsigned*)(void*)&ctx_seq[(size_t)t * (B_ * H_) + pi],
                               hp, __ATOMIC_RELAXED, __HIP_MEMORY_SCOPE_AGENT);
            __hip_atomic_store((unsigned*)(void*)
                               &loring[(size_t)(t & (LORING_SLOTS - 1)) * (B_ * H_) + pi],
                               lp, __ATOMIC_RELAXED, __HIP_MEMORY_SCOPE_AGENT);
            if (t == T_ - 1)   // survives P-GEMM overwriting loring
                *(unsigned*)(void*)&enc_lo_fin[pi] = lp;
        }

        // ---- arrive (release handled by last arriver) ----
        if (t != T_ - 1) {
            __syncthreads();   // drains vmcnt: stores IC-visible before arrival
            if (tid == 0) {
                const unsigned arrived =
                    __hip_atomic_fetch_add(&bar[0], 1u, __ATOMIC_RELAXED,
                                           __HIP_MEMORY_SCOPE_AGENT) + 1;
                if (arrived == (unsigned)(t + 1) * 256u)
                    __hip_atomic_store(&bar[1], (unsigned)(t + 1),
                                       __ATOMIC_RELAXED, __HIP_MEMORY_SCOPE_AGENT);
            }
        }
    }
}

// ---- fused LSTM step (decoder). Block: 64 batch rows x 16 gate-cols. -------
// grid (H/4 = 256 colgroups, 2 row-halves). A-side h/x PANEL layout.
template<bool WSPLIT, bool XSPLIT, int KX>
__global__ __launch_bounds__(256) void lstm_mfma(
    const ushort* __restrict__ h_hi, const ushort* __restrict__ h_lo,
    const void* __restrict__ x_p, const ushort* __restrict__ x_lo,
    const void* __restrict__ Whh_a, const void* __restrict__ Whh_b,
    const void* __restrict__ Wih_a, const void* __restrict__ Wih_b,
    const float* __restrict__ bih, const float* __restrict__ bhh,
    const float* __restrict__ c_in, float* __restrict__ c_out,
    ushort* __restrict__ h_out_hi, ushort* __restrict__ h_out_lo)
{
    __shared__ float Gt[16][65];
    const int tid = threadIdx.x;
    const int wave = tid >> 6, lane = tid & 63;
    const int quad = lane >> 4, l15 = lane & 15;
    const int h0 = blockIdx.x << 2;
    const int mbase = (blockIdx.y << 6) + (wave << 4);
    const int arow = mbase + l15;
    const int wr = ((l15 >> 2) * H_) + h0 + (l15 & 3);   // gate*H + h index

    f32x4 acc0 = {0.f,0.f,0.f,0.f}, acc1 = acc0, acc2 = acc0;

    // segment 1: h @ Whh^T, K = 1024, A split (hi+lo), panel A
    {
        const size_t woff = (size_t)wr * H_;
        #pragma unroll 4
        for (int kc = 0; kc < H_; kc += 32) {
            const int ko = kc + quad * 8;
            bf16x8 bh, bl;
            if constexpr (WSPLIT) {
                bh = ld8((const ushort*)Whh_a + woff + ko);
                bl = ld8((const ushort*)Whh_b + woff + ko);
            } else {
                split8((const float*)Whh_a + woff + ko, bh, bl);
            }
            const bf16x8 ah = ld8p(h_hi, arow, ko);
            const bf16x8 al = ld8p(h_lo, arow, ko);
            acc0 = mfma16(ah, bh, acc0);
            acc1 = mfma16(ah, bl, acc1);
            acc2 = mfma16(al, bh, acc2);
        }
    }
    // segment 2: x @ Wih^T, K = KX (x panel when XSPLIT)
    {
        const size_t woff = (size_t)wr * KX;
        #pragma unroll 2
        for (int kc = 0; kc < KX; kc += 32) {
            const int ko = kc + quad * 8;
            bf16x8 bh, bl;
            if constexpr (WSPLIT) {
                bh = ld8((const ushort*)Wih_a + woff + ko);
                bl = ld8((const ushort*)Wih_b + woff + ko);
            } else {
                split8((const float*)Wih_a + woff + ko, bh, bl);
            }
            bf16x8 ah, al;
            if constexpr (XSPLIT) {
                ah = ld8p((const ushort*)x_p, arow, ko);
                al = ld8p(x_lo, arow, ko);
            } else {
                split8((const float*)x_p + (size_t)arow * KX + ko, ah, al);
            }
            acc0 = mfma16(ah, bh, acc0);
            acc1 = mfma16(ah, bl, acc1);
            acc2 = mfma16(al, bh, acc2);
        }
    }
    // gate exchange: Gt[col][local_row]; D: row=quad*4+r, col=l15
    #pragma unroll
    for (int r = 0; r < 4; r++)
        Gt[l15][(wave << 4) + quad * 4 + r] = acc0[r] + acc1[r] + acc2[r];
    __syncthreads();

    // cell update: thread -> (local batch row, h-local)
    const int bl_ = tid >> 2, hl = tid & 3;
    const int b = (blockIdx.y << 6) + bl_;
    const int hidx = h0 + hl;
    const float gi = Gt[hl][bl_]      + bih[hidx]          + bhh[hidx];
    const float gf = Gt[4 + hl][bl_]  + bih[H_ + hidx]     + bhh[H_ + hidx];
    const float gg = Gt[8 + hl][bl_]  + bih[2 * H_ + hidx] + bhh[2 * H_ + hidx];
    const float go = Gt[12 + hl][bl_] + bih[3 * H_ + hidx] + bhh[3 * H_ + hidx];
    const float ig = fast_sigmoid(gi), fg = fast_sigmoid(gf);
    const float gt = fast_tanh(gg),    og = fast_sigmoid(go);
    const float cold = c_in[b * H_ + hidx];
    const float cnew = fg * cold + ig * gt;
    const float hnew = og * fast_tanh(cnew);
    c_out[b * H_ + hidx] = cnew;
    const ushort hh = f2bf(hnew);
    const size_t op = ((size_t)(hidx >> 2) * B_ + b) * 4 + (hidx & 3);   // panel
    h_out_hi[op] = hh;
    h_out_lo[op] = f2bf(hnew - bf2f(hh));
}

// ---- generic MFMA GEMM: C = act(A @ W^T + bias) ----------------------------
// grid (N/(16*NT), M/64). Wave = 1 M-tile(16 rows) x NT N-tiles.
// APANEL: A in panel layout. OM: 0=f32 row-major, 3=split bf16 PANEL out,
// 4=fp16 dual-region row-major (idx<HALF -> out0)
template<bool A_LO, int NT, int OM, bool RELU, int K, bool APANEL>
__global__ __launch_bounds__(256) void gemm_mfma(
    const ushort* __restrict__ Ahi, const ushort* __restrict__ Alo, int lda,
    const ushort* __restrict__ Whi, const ushort* __restrict__ Wlo,
    const float* __restrict__ bias,
    void* __restrict__ out0, void* __restrict__ out1, int ldc)
{
    const int tid = threadIdx.x;
    const int wave = tid >> 6, lane = tid & 63;
    const int quad = lane >> 4, l15 = lane & 15;
    const int colbase = (blockIdx.x * NT) << 4;
    const int row = (blockIdx.y << 6) + (wave << 4) + l15;
    const size_t aoff = (size_t)row * lda;

    f32x4 acc0[NT], acc1[NT], acc2[NT];
    #pragma unroll
    for (int nt = 0; nt < NT; nt++) {
        acc0[nt] = {0.f,0.f,0.f,0.f}; acc1[nt] = acc0[nt]; acc2[nt] = acc0[nt];
    }
    size_t woff[NT];
    #pragma unroll
    for (int nt = 0; nt < NT; nt++)
        woff[nt] = (size_t)(colbase + (nt << 4) + l15) * K;

    #pragma unroll 2
    for (int kc = 0; kc < K; kc += 32) {
        const int ko = kc + quad * 8;
        const bf16x8 ah = APANEL ? ld8p(Ahi, row, ko) : ld8(Ahi + aoff + ko);
        bf16x8 al;
        if (A_LO) al = APANEL ? ld8p(Alo, row, ko) : ld8(Alo + aoff + ko);
        #pragma unroll
        for (int nt = 0; nt < NT; nt++) {
            const bf16x8 bh = ld8(Whi + woff[nt] + ko);
            const bf16x8 bl = ld8(Wlo + woff[nt] + ko);
            acc0[nt] = mfma16(ah, bh, acc0[nt]);
            acc1[nt] = mfma16(ah, bl, acc1[nt]);
            if (A_LO) acc2[nt] = mfma16(al, bh, acc2[nt]);
        }
    }
    const size_t orow0 = ((size_t)blockIdx.y << 6) + (wave << 4) + quad * 4;
    const size_t HALF_IDX = (size_t)32768 * 1024;   // P region boundary
    #pragma unroll
    for (int nt = 0; nt < NT; nt++) {
        const int col = colbase + (nt << 4) + l15;
        const float bv = bias ? bias[col] : 0.f;
        #pragma unroll
        for (int r = 0; r < 4; r++) {
            float v = acc0[nt][r] + acc1[nt][r] + (A_LO ? acc2[nt][r] : 0.f) + bv;
            if (RELU) v = fmaxf(v, 0.f);
            const size_t idx = (orow0 + r) * (size_t)ldc + col;
            if constexpr (OM == 0) {
                ((float*)out0)[idx] = v;
            } else if constexpr (OM == 3) {     // panel bf16 hi/lo
                const size_t idxp = ((size_t)(col >> 2) * B_ + (orow0 + r)) * 4 + (col & 3);
                const ushort h = f2bf(v);
                ((ushort*)out0)[idxp] = h;
                ((ushort*)out1)[idxp] = f2bf(v - bf2f(h));
            } else {   // OM == 4: fp16 dual region, row-major
                if (idx < HALF_IDX) ((_Float16*)out0)[idx] = (_Float16)v;
                else                ((_Float16*)out1)[idx - HALF_IDX] = (_Float16)v;
            }
        }
    }
}

// ---- scores[b][t] = sum_h v[h]*tanh(q[b][h] + P[t][b][h]); P fp16 2-region -
__global__ __launch_bounds__(256) void attn_score_kernel(
    const float* __restrict__ q,
    const _Float16* __restrict__ P0, const _Float16* __restrict__ P1,
    const float* __restrict__ v, float* __restrict__ scores)
{
    const int wave = threadIdx.x >> 6, lane = threadIdx.x & 63;
    const int p = (blockIdx.x << 2) + wave;
    const int t = p >> 7, b = p & 127;
    const size_t base = (size_t)(t * B_ + b) * H_ + (lane << 4);
    const size_t HALF_IDX = (size_t)32768 * 1024;
    const _Float16* pp = (base < HALF_IDX) ? (P0 + base) : (P1 + (base - HALF_IDX));

    const half8 u0 = *(const half8*)(const void*)pp;
    const half8 u1 = *(const half8*)(const void*)(pp + 8);
    float pv[16];
    #pragma unroll
    for (int j = 0; j < 8; j++) { pv[j] = (float)u0[j]; pv[8 + j] = (float)u1[j]; }

    const float* qp = q + b * H_ + (lane << 4);
    const float* vp = v + (lane << 4);
    float sum = 0.f;
    #pragma unroll
    for (int j0 = 0; j0 < 16; j0 += 4) {
        const float4 qv = *(const float4*)(qp + j0);
        const float4 vv = *(const float4*)(vp + j0);
        sum += vv.x * fast_tanh(qv.x + pv[j0 + 0]);
        sum += vv.y * fast_tanh(qv.y + pv[j0 + 1]);
        sum += vv.z * fast_tanh(qv.z + pv[j0 + 2]);
        sum += vv.w * fast_tanh(qv.w + pv[j0 + 3]);
    }
    #pragma unroll
    for (int off = 32; off; off >>= 1) sum += __shfl_down(sum, off);
    if (lane == 0) scores[b * T_ + t] = sum;
}

// ---- softmax over t; reads scores[b][t], writes transposed scT[t][b] -------
__global__ __launch_bounds__(256) void softmax_kernel(
    const float* __restrict__ scores, float* __restrict__ scT)
{
    __shared__ float red[256];
    const int b = blockIdx.x, tid = threadIdx.x;
    const float s0 = scores[b * T_ + tid];
    const float s1 = scores[b * T_ + tid + 256];
    red[tid] = fmaxf(s0, s1);
    __syncthreads();
    for (int off = 128; off; off >>= 1) {
        if (tid < off) red[tid] = fmaxf(red[tid], red[tid + off]);
        __syncthreads();
    }
    const float mx = red[0];
    __syncthreads();
    const float e0 = __expf(s0 - mx), e1 = __expf(s1 - mx);
    red[tid] = e0 + e1;
    __syncthreads();
    for (int off = 128; off; off >>= 1) {
        if (tid < off) red[tid] += red[tid + off];
        __syncthreads();
    }
    const float inv = 1.f / red[0];
    scT[tid * B_ + b] = e0 * inv;
    scT[(tid + 256) * B_ + b] = e1 * inv;
}

// ---- context (panel): ctx_hi/lo[c][b][4] = sum_t scT[t][b]*ctx[t][c][b][4] -
__global__ __launch_bounds__(256) void attn_context_kernel(
    const float* __restrict__ scT, const ushort* __restrict__ ctx,
    ushort* __restrict__ chi, ushort* __restrict__ clo)
{
    const int u = blockIdx.x * 256 + threadIdx.x;   // 32768 threads
    const int c = u >> 7, b = u & 127;
    const ushort* cp = ctx + ((size_t)(c * B_ + b) << 2);
    const float* wp = scT + b;
    float a0 = 0.f, a1 = 0.f, a2 = 0.f, a3 = 0.f;
    #pragma unroll 4
    for (int t = 0; t < T_; t++) {
        const float w = wp[t << 7];
        const u64 raw = *(const u64*)(const void*)(cp + (size_t)t * (B_ * H_));
        a0 += w * bf2f((ushort)raw);
        a1 += w * bf2f((ushort)(raw >> 16));
        a2 += w * bf2f((ushort)(raw >> 32));
        a3 += w * bf2f((ushort)(raw >> 48));
    }
    const size_t i0 = (size_t)(c * B_ + b) << 2;
    const ushort h0 = f2bf(a0), h1 = f2bf(a1), h2 = f2bf(a2), h3 = f2bf(a3);
    const ushort l0 = f2bf(a0 - bf2f(h0)), l1 = f2bf(a1 - bf2f(h1));
    const ushort l2 = f2bf(a2 - bf2f(h2)), l3 = f2bf(a3 - bf2f(h3));
    *(u64*)(void*)&chi[i0] = (u64)h0 | ((u64)h1 << 16) | ((u64)h2 << 32) | ((u64)h3 << 48);
    *(u64*)(void*)&clo[i0] = (u64)l0 | ((u64)l1 << 16) | ((u64)l2 << 32) | ((u64)l3 << 48);
}

// ---------------------------------------------------------------------------
extern "C" void kernel_launch(void* const* d_in, const int* in_sizes, int n_in,
                              void* d_out, int out_size, void* d_ws, size_t ws_size,
                              hipStream_t stream)
{
    const float* input_seq = (const float*)d_in[0];
    const float* W_ih_enc  = (const float*)d_in[1];
    const float* W_hh_enc  = (const float*)d_in[2];
    const float* b_ih_enc  = (const float*)d_in[3];
    const float* b_hh_enc  = (const float*)d_in[4];
    const float* W_attn    = (const float*)d_in[5];
    const float* b_attn    = (const float*)d_in[6];
    const float* v         = (const float*)d_in[7];
    const float* W_ih_dec  = (const float*)d_in[8];
    const float* W_hh_dec  = (const float*)d_in[9];
    const float* b_ih_dec  = (const float*)d_in[10];
    const float* b_hh_dec  = (const float*)d_in[11];
    const float* W_dec     = (const float*)d_in[12];
    const float* b_dec     = (const float*)d_in[13];
    const float* W_out     = (const float*)d_in[14];
    const float* b_out     = (const float*)d_in[15];
    float* out = (float*)d_out;
    const int LEN = out_size / (B_ * O_);   // 30
    const int BH = B_ * H_;

    char* ws = (char*)d_ws;
    size_t off = 0;
    auto aus = [&](size_t n) { ushort* p = (ushort*)(ws + off); off += n * 2; return p; };
    auto af  = [&](size_t n) { float*  p = (float*) (ws + off); off += n * 4; return p; };

    // pre-split weights (hot / MFMA-consumed). Decoder LSTM W split on the fly.
    ushort* WhhE_h = aus((size_t)4*H_*H_); ushort* WhhE_l = aus((size_t)4*H_*H_);
    ushort* WihE_h = aus((size_t)4*H_*I_); ushort* WihE_l = aus((size_t)4*H_*I_);
    ushort* Wh_h   = aus((size_t)H_*H_);   ushort* Wh_l   = aus((size_t)H_*H_);
    ushort* Wc_h   = aus((size_t)H_*H_);   ushort* Wc_l   = aus((size_t)H_*H_);
    ushort* Wdec_h = aus((size_t)H_*H_);   ushort* Wdec_l = aus((size_t)H_*H_);
    ushort* Wout_h = aus((size_t)O_*H_);   ushort* Wout_l = aus((size_t)O_*H_);

    ushort* ctx_seq = aus((size_t)T_ * BH);          // hi history, panel layout
    ushort* hzero   = aus(BH);
    ushort* enc_lo_fin = aus(BH);                    // final lo (post-P-GEMM use)
    ushort* hd_hi0  = aus(BH); ushort* hd_hi1  = aus(BH);
    ushort* hd_lo0  = aus(BH); ushort* hd_lo1  = aus(BH);
    ushort* ctx_hi  = aus(BH); ushort* ctx_lo  = aus(BH);
    ushort* d1_hi   = aus(BH); ushort* d1_lo   = aus(BH);
    float*  cbuf    = af(BH);
    float*  qbuf    = af(BH);
    float*  scores  = af(B_ * T_);
    float*  scT     = af(B_ * T_);
    unsigned* barbuf = (unsigned*)(ws + off); off += 256;   // grid-barrier state

    // lo ring: 256 slots x 256KB = 67.1 MB. Dead after encoder -> P1 aliases it.
    ushort* loring = aus((size_t)LORING_SLOTS * BH);
    const size_t P_HALF = (size_t)(T_ / 2) * BH * 2;   // 67,108,864 == loring size
    _Float16* P1 = (_Float16*)loring;
    _Float16* P0;
    if (ws_size >= off + P_HALF) {            // spare ws for P0
        P0 = (_Float16*)(ws + off);
    } else {                                   // alias input_seq (dead after enc)
        P0 = (_Float16*)const_cast<float*>(input_seq);
    }

    // ---- weight split pre-pass ----
    auto spl = [&](const float* src, int srcld, int coloff, ushort* hi, ushort* lo,
                   int R, int K) {
        split_w<<<dim3(K / 256, R), 256, 0, stream>>>(src, srcld, coloff, hi, lo, K);
    };
    spl(W_hh_enc, H_,     0,  WhhE_h, WhhE_l, 4 * H_, H_);
    spl(W_ih_enc, I_,     0,  WihE_h, WihE_l, 4 * H_, I_);
    spl(W_attn,   2 * H_, 0,  Wh_h,   Wh_l,   H_,     H_);
    spl(W_attn,   2 * H_, H_, Wc_h,   Wc_l,   H_,     H_);
    spl(W_dec,    H_,     0,  Wdec_h, Wdec_l, H_,     H_);
    spl(W_out,    H_,     0,  Wout_h, Wout_l, O_,     H_);

    hipMemsetAsync(hzero,  0, (size_t)BH * 2, stream);   // h_{-1} = lo_{-1} = 0
    hipMemsetAsync(barbuf, 0, 256, stream);

    // ---- encoder: ONE persistent kernel, 512 steps, fence-free barriers ----
    enc_persistent<<<dim3(H_ / 4), 512, ENC_SMEM_BYTES, stream>>>(
        input_seq, WhhE_h, WhhE_l, WihE_h, WihE_l, b_ih_enc, b_hh_enc,
        hzero, ctx_seq, loring, enc_lo_fin, barbuf);
    // enc final: hi = ctx_seq[511] (panel), lo = enc_lo_fin (panel)

    // ---- P = ctx_seq @ W_c^T + b_attn  (fp16 row-major, dual region;
    //      P1 overwrites loring, P0 may overwrite input_seq — both dead) ----
    gemm_mfma<false, 8, 4, false, H_, true><<<dim3(8, (T_ * B_) / 64), 256, 0, stream>>>(
        ctx_seq, nullptr, H_, Wc_h, Wc_l, b_attn, P0, P1, H_);

    // ---- decoder ----
    hipMemsetAsync(cbuf, 0, (size_t)BH * 4, stream);
    ushort* dhh[2] = {hd_hi0, hd_hi1};
    ushort* dhl[2] = {hd_lo0, hd_lo1};
    for (int s = 0; s < LEN; s++) {
        const ushort* hi_in = (s == 0) ? ctx_seq + (size_t)(T_ - 1) * BH : dhh[s & 1];
        const ushort* lo_in = (s == 0) ? enc_lo_fin : dhl[s & 1];

        // q = h @ W_h^T (bias folded into P)
        gemm_mfma<true, 1, 0, false, H_, true><<<dim3(H_ / 16, 2), 256, 0, stream>>>(
            hi_in, lo_in, H_, Wh_h, Wh_l, nullptr, qbuf, nullptr, H_);
        attn_score_kernel<<<T_ * B_ / 4, 256, 0, stream>>>(qbuf, P0, P1, v, scores);
        softmax_kernel<<<B_, 256, 0, stream>>>(scores, scT);
        attn_context_kernel<<<BH / 4 / 256, 256, 0, stream>>>(scT, ctx_seq, ctx_hi, ctx_lo);
        // decoder LSTM cell (x = context panel; weights split on the fly)
        lstm_mfma<false, true, H_><<<dim3(H_ / 4, 2), 256, 0, stream>>>(
            hi_in, lo_in, (const void*)ctx_hi, ctx_lo,
            W_hh_dec, nullptr, W_ih_dec, nullptr, b_ih_dec, b_hh_dec,
            cbuf, cbuf, dhh[(s + 1) & 1], dhl[(s + 1) & 1]);
        // d1 = relu(h @ W_dec^T + b_dec) -> split (panel out)
        gemm_mfma<true, 1, 3, true, H_, true><<<dim3(H_ / 16, 2), 256, 0, stream>>>(
            dhh[(s + 1) & 1], dhl[(s + 1) & 1], H_, Wdec_h, Wdec_l, b_dec,
            d1_hi, d1_lo, H_);
        // out = d1 @ W_out^T + b_out  (fp32 row-major final output)
        gemm_mfma<true, 1, 0, false, H_, true><<<dim3(O_ / 16, 2), 256, 0, stream>>>(
            d1_hi, d1_lo, H_, Wout_h, Wout_l, b_out,
            out + (size_t)s * B_ * O_, nullptr, O_);
    }
    (void)in_sizes; (void)n_in;
}